// Round 1
// baseline (3730.243 us; speedup 1.0000x reference)
//
#include <hip/hip_runtime.h>
#include <math.h>

#define BB 2
#define HIDC 64
#define HWN 1024

// ---------------------------------------------------------------- ConvLSTM cell
struct CellArgs {
  const float* x[2]; long xbs;
  const float* h[2]; const float* c[2];
  const float* w[2]; const float* bias[2];
  float* ho[2]; float* co[2];
};

template<int CX>
__global__ __launch_bounds__(256) void cell_kernel(CellArgs a) {
  constexpr int CT = CX + HIDC;          // total input channels (concat x,h)
  __shared__ float sIn[CT * 48];         // [CT][6][8] padded rows
  __shared__ float sG[256 * 17];         // gates [256 oc][16 px] pad 17
  const int tile = blockIdx.x;           // 64 tiles of 4x4
  const int b = blockIdx.y;
  const int st = blockIdx.z;
  const int ty0 = (tile >> 3) << 2, tx0 = (tile & 7) << 2;
  const float* xp = a.x[st] + (size_t)b * a.xbs;
  const float* hp = a.h[st] + (size_t)b * HIDC * HWN;

  for (int idx = threadIdx.x; idx < CT * 36; idx += 256) {
    int ic = idx / 36, pos = idx - ic * 36;
    int iy = pos / 6, ix = pos - iy * 6;
    int gy = ty0 - 1 + iy, gx = tx0 - 1 + ix;
    float v = 0.f;
    if ((unsigned)gy < 32u && (unsigned)gx < 32u) {
      v = (ic < CX) ? xp[ic * HWN + gy * 32 + gx]
                    : hp[(ic - CX) * HWN + gy * 32 + gx];
    }
    sIn[ic * 48 + iy * 8 + ix] = v;
  }
  __syncthreads();

  const int oc = threadIdx.x;            // 0..255 (4*HID gate channels)
  float acc[16];
  {
    const float bv = a.bias[st][oc];
#pragma unroll
    for (int p = 0; p < 16; ++p) acc[p] = bv;
  }
  const float* wp = a.w[st] + (size_t)oc * CT * 9;
  for (int ic = 0; ic < CT; ++ic) {
    float w9[9];
#pragma unroll
    for (int t = 0; t < 9; ++t) w9[t] = wp[ic * 9 + t];
    float in[36];
#pragma unroll
    for (int iy = 0; iy < 6; ++iy) {
      float4 v4 = *(const float4*)&sIn[ic * 48 + iy * 8];
      float2 v2 = *(const float2*)&sIn[ic * 48 + iy * 8 + 4];
      in[iy * 6 + 0] = v4.x; in[iy * 6 + 1] = v4.y; in[iy * 6 + 2] = v4.z;
      in[iy * 6 + 3] = v4.w; in[iy * 6 + 4] = v2.x; in[iy * 6 + 5] = v2.y;
    }
#pragma unroll
    for (int ky = 0; ky < 3; ++ky)
#pragma unroll
      for (int kx = 0; kx < 3; ++kx) {
        const float wv = w9[ky * 3 + kx];
#pragma unroll
        for (int py = 0; py < 4; ++py)
#pragma unroll
          for (int px = 0; px < 4; ++px)
            acc[py * 4 + px] += wv * in[(py + ky) * 6 + (px + kx)];
      }
  }
#pragma unroll
  for (int p = 0; p < 16; ++p) sG[oc * 17 + p] = acc[p];
  __syncthreads();

  const float* cp = a.c[st] + (size_t)b * HIDC * HWN;
  float* hop = a.ho[st] + (size_t)b * HIDC * HWN;
  float* cop = a.co[st] + (size_t)b * HIDC * HWN;
  for (int idx = threadIdx.x; idx < HIDC * 16; idx += 256) {
    int hc = idx >> 4, p = idx & 15;
    float gi = sG[hc * 17 + p];
    float gf = sG[(hc + 64) * 17 + p];
    float go = sG[(hc + 128) * 17 + p];
    float gg = sG[(hc + 192) * 17 + p];
    gi = 1.f / (1.f + expf(-gi));
    gf = 1.f / (1.f + expf(-gf));
    go = 1.f / (1.f + expf(-go));
    gg = tanhf(gg);
    int off = hc * HWN + (ty0 + (p >> 2)) * 32 + tx0 + (p & 3);
    float cn = gf * cp[off] + gi * gg;
    cop[off] = cn;
    hop[off] = go * tanhf(cn);
  }
}

// ---------------------------------------------------------------- QKV (1x1 convs)
struct QkvArgs {
  const float* xq[4]; const float* xkv[4];
  const float* w[4]; const float* bias[4];
  float* Q; float* K; float* V;          // each [4][B][1024][64]
};

__global__ __launch_bounds__(256) void qkv_kernel(QkvArgs a) {
  __shared__ float sWt[64 * 68];         // [c][o] transposed, pad 68
  const int ptile = blockIdx.x, b = blockIdx.y;
  const int attn = blockIdx.z / 3, proj = blockIdx.z % 3;
  const float* x = (proj == 0 ? a.xq[attn] : a.xkv[attn]) + (size_t)b * HIDC * HWN;
  const float* w = a.w[attn] + proj * 64 * 64;
  const float* bias = a.bias[attn] + proj * 64;
  float* dst = (proj == 0 ? a.Q : (proj == 1 ? a.K : a.V)) +
               ((size_t)attn * BB + b) * HWN * HIDC;
  for (int i = threadIdx.x; i < 4096; i += 256) {
    int o = i >> 6, c = i & 63;
    sWt[c * 68 + o] = w[i];
  }
  __syncthreads();
  const int og = threadIdx.x & 3, pq = threadIdx.x >> 2;
  const int p0 = ptile * 256 + pq * 4;
  float acc[4][16];
#pragma unroll
  for (int k = 0; k < 16; ++k) {
    float bv = bias[og * 16 + k];
    acc[0][k] = bv; acc[1][k] = bv; acc[2][k] = bv; acc[3][k] = bv;
  }
  for (int c = 0; c < 64; ++c) {
    float4 xv = *(const float4*)&x[c * HWN + p0];
#pragma unroll
    for (int k = 0; k < 16; k += 4) {
      float4 wv = *(const float4*)&sWt[c * 68 + og * 16 + k];
      acc[0][k+0] += xv.x*wv.x; acc[0][k+1] += xv.x*wv.y; acc[0][k+2] += xv.x*wv.z; acc[0][k+3] += xv.x*wv.w;
      acc[1][k+0] += xv.y*wv.x; acc[1][k+1] += xv.y*wv.y; acc[1][k+2] += xv.y*wv.z; acc[1][k+3] += xv.y*wv.w;
      acc[2][k+0] += xv.z*wv.x; acc[2][k+1] += xv.z*wv.y; acc[2][k+2] += xv.z*wv.z; acc[2][k+3] += xv.z*wv.w;
      acc[3][k+0] += xv.w*wv.x; acc[3][k+1] += xv.w*wv.y; acc[3][k+2] += xv.w*wv.z; acc[3][k+3] += xv.w*wv.w;
    }
  }
#pragma unroll
  for (int px = 0; px < 4; ++px) {
    float* d = dst + (size_t)(p0 + px) * HIDC + og * 16;
#pragma unroll
    for (int k = 0; k < 16; k += 4) {
      float4 v; v.x = acc[px][k]; v.y = acc[px][k+1]; v.z = acc[px][k+2]; v.w = acc[px][k+3];
      *(float4*)&d[k] = v;
    }
  }
}

// ---------------------------------------------------------------- flash attention
struct AttnArgs {
  const float* xq[4]; float* out[4];
  const float* Q; const float* K; const float* V;
};

__global__ __launch_bounds__(256) void attn_kernel(AttnArgs a) {
  __shared__ float sQt[64 * 36];   // [c][r] pad 36 (scaled by 1/8)
  __shared__ float sKt[64 * 68];   // [c][j] pad 68
  __shared__ float sV [64 * 68];   // [j][c] pad 68
  __shared__ float sPt[64 * 36];   // [j][r] pad 36
  const int qt = blockIdx.x, b = blockIdx.y, at = blockIdx.z;
  const size_t base = ((size_t)at * BB + b) * HWN * HIDC;
  const float* Qp = a.Q + base + (size_t)qt * 32 * HIDC;
  const float* Kp = a.K + base;
  const float* Vp = a.V + base;
  const int tid = threadIdx.x;
  {
    int r = tid >> 3, c0 = (tid & 7) * 8;
    const float* q = Qp + r * HIDC + c0;
#pragma unroll
    for (int k = 0; k < 8; k += 4) {
      float4 v = *(const float4*)&q[k];
      sQt[(c0 + k + 0) * 36 + r] = v.x * 0.125f;
      sQt[(c0 + k + 1) * 36 + r] = v.y * 0.125f;
      sQt[(c0 + k + 2) * 36 + r] = v.z * 0.125f;
      sQt[(c0 + k + 3) * 36 + r] = v.w * 0.125f;
    }
  }
  const int tc = tid & 15, tr = tid >> 4;
  const int r0 = tr * 2, j0 = tc * 4;
  float m0 = -1e30f, m1 = -1e30f, l0 = 0.f, l1 = 0.f;
  float o00=0,o01=0,o02=0,o03=0,o10=0,o11=0,o12=0,o13=0;

  for (int kt = 0; kt < 16; ++kt) {
    __syncthreads();
    {
      int j = tid >> 2, cs = (tid & 3) * 16;
      const float* kp = Kp + (size_t)(kt * 64 + j) * HIDC + cs;
      const float* vp = Vp + (size_t)(kt * 64 + j) * HIDC + cs;
#pragma unroll
      for (int k = 0; k < 16; k += 4) {
        float4 kv = *(const float4*)&kp[k];
        sKt[(cs + k + 0) * 68 + j] = kv.x;
        sKt[(cs + k + 1) * 68 + j] = kv.y;
        sKt[(cs + k + 2) * 68 + j] = kv.z;
        sKt[(cs + k + 3) * 68 + j] = kv.w;
        *(float4*)&sV[j * 68 + cs + k] = *(const float4*)&vp[k];
      }
    }
    __syncthreads();
    float s00=0,s01=0,s02=0,s03=0,s10=0,s11=0,s12=0,s13=0;
#pragma unroll 4
    for (int c = 0; c < 64; ++c) {
      float2 qv = *(const float2*)&sQt[c * 36 + r0];
      float4 kv = *(const float4*)&sKt[c * 68 + j0];
      s00 += qv.x*kv.x; s01 += qv.x*kv.y; s02 += qv.x*kv.z; s03 += qv.x*kv.w;
      s10 += qv.y*kv.x; s11 += qv.y*kv.y; s12 += qv.y*kv.z; s13 += qv.y*kv.w;
    }
    float mt0 = fmaxf(fmaxf(s00, s01), fmaxf(s02, s03));
    float mt1 = fmaxf(fmaxf(s10, s11), fmaxf(s12, s13));
#pragma unroll
    for (int d = 1; d < 16; d <<= 1) {
      mt0 = fmaxf(mt0, __shfl_xor(mt0, d));
      mt1 = fmaxf(mt1, __shfl_xor(mt1, d));
    }
    float mn0 = fmaxf(m0, mt0), mn1 = fmaxf(m1, mt1);
    float al0 = __expf(m0 - mn0), al1 = __expf(m1 - mn1);
    s00 = __expf(s00 - mn0); s01 = __expf(s01 - mn0);
    s02 = __expf(s02 - mn0); s03 = __expf(s03 - mn0);
    s10 = __expf(s10 - mn1); s11 = __expf(s11 - mn1);
    s12 = __expf(s12 - mn1); s13 = __expf(s13 - mn1);
    float ps0 = s00 + s01 + s02 + s03, ps1 = s10 + s11 + s12 + s13;
#pragma unroll
    for (int d = 1; d < 16; d <<= 1) {
      ps0 += __shfl_xor(ps0, d);
      ps1 += __shfl_xor(ps1, d);
    }
    l0 = l0 * al0 + ps0; l1 = l1 * al1 + ps1;
    m0 = mn0; m1 = mn1;
    o00*=al0; o01*=al0; o02*=al0; o03*=al0;
    o10*=al1; o11*=al1; o12*=al1; o13*=al1;
    float2 pv;
    pv.x=s00; pv.y=s10; *(float2*)&sPt[(j0+0)*36 + r0] = pv;
    pv.x=s01; pv.y=s11; *(float2*)&sPt[(j0+1)*36 + r0] = pv;
    pv.x=s02; pv.y=s12; *(float2*)&sPt[(j0+2)*36 + r0] = pv;
    pv.x=s03; pv.y=s13; *(float2*)&sPt[(j0+3)*36 + r0] = pv;
    __syncthreads();
#pragma unroll 4
    for (int j = 0; j < 64; ++j) {
      float2 pj = *(const float2*)&sPt[j * 36 + r0];
      float4 vv = *(const float4*)&sV[j * 68 + j0];
      o00 += pj.x*vv.x; o01 += pj.x*vv.y; o02 += pj.x*vv.z; o03 += pj.x*vv.w;
      o10 += pj.y*vv.x; o11 += pj.y*vv.y; o12 += pj.y*vv.z; o13 += pj.y*vv.w;
    }
  }
  const float* xq = a.xq[at] + (size_t)b * HIDC * HWN;
  float* op = a.out[at] + (size_t)b * HIDC * HWN;
  const int p0 = qt * 32 + r0;
  const float inv0 = 1.f / l0, inv1 = 1.f / l1;
  op[(j0+0)*HWN + p0]   = o00*inv0 + xq[(j0+0)*HWN + p0];
  op[(j0+1)*HWN + p0]   = o01*inv0 + xq[(j0+1)*HWN + p0];
  op[(j0+2)*HWN + p0]   = o02*inv0 + xq[(j0+2)*HWN + p0];
  op[(j0+3)*HWN + p0]   = o03*inv0 + xq[(j0+3)*HWN + p0];
  op[(j0+0)*HWN + p0+1] = o10*inv1 + xq[(j0+0)*HWN + p0+1];
  op[(j0+1)*HWN + p0+1] = o11*inv1 + xq[(j0+1)*HWN + p0+1];
  op[(j0+2)*HWN + p0+1] = o12*inv1 + xq[(j0+2)*HWN + p0+1];
  op[(j0+3)*HWN + p0+1] = o13*inv1 + xq[(j0+3)*HWN + p0+1];
}

// ---------------------------------------------------------------- decoder
struct Dec1Args { const float* in[2]; const float* w; const float* b; float* tmp; };

__global__ __launch_bounds__(256) void dec1_kernel(Dec1Args a) {
  __shared__ float sIn[64 * 48];
  const int tile = blockIdx.x, b = blockIdx.y, st = blockIdx.z;
  const int ty0 = (tile >> 3) << 2, tx0 = (tile & 7) << 2;
  const float* ip = a.in[st] + (size_t)b * HIDC * HWN;
  for (int idx = threadIdx.x; idx < 64 * 36; idx += 256) {
    int ic = idx / 36, pos = idx - ic * 36;
    int iy = pos / 6, ix = pos - iy * 6;
    int gy = ty0 - 1 + iy, gx = tx0 - 1 + ix;
    float v = 0.f;
    if ((unsigned)gy < 32u && (unsigned)gx < 32u) v = ip[ic * HWN + gy * 32 + gx];
    sIn[ic * 48 + iy * 8 + ix] = v;
  }
  __syncthreads();
  const int oc = threadIdx.x & 63, ps = threadIdx.x >> 6;
  float acc0, acc1, acc2, acc3;
  acc0 = acc1 = acc2 = acc3 = a.b[oc];
  const float* wp = a.w + (size_t)oc * 64 * 9;
  for (int ic = 0; ic < 64; ++ic) {
    float in[18];
#pragma unroll
    for (int ry = 0; ry < 3; ++ry) {
      float4 v4 = *(const float4*)&sIn[ic * 48 + (ps + ry) * 8];
      float2 v2 = *(const float2*)&sIn[ic * 48 + (ps + ry) * 8 + 4];
      in[ry*6+0]=v4.x; in[ry*6+1]=v4.y; in[ry*6+2]=v4.z; in[ry*6+3]=v4.w;
      in[ry*6+4]=v2.x; in[ry*6+5]=v2.y;
    }
#pragma unroll
    for (int ky = 0; ky < 3; ++ky)
#pragma unroll
      for (int kx = 0; kx < 3; ++kx) {
        float wv = wp[ic * 9 + ky * 3 + kx];
        acc0 += wv * in[ky * 6 + kx + 0];
        acc1 += wv * in[ky * 6 + kx + 1];
        acc2 += wv * in[ky * 6 + kx + 2];
        acc3 += wv * in[ky * 6 + kx + 3];
      }
  }
  float4 o;
  o.x = fmaxf(acc0, 0.f); o.y = fmaxf(acc1, 0.f);
  o.z = fmaxf(acc2, 0.f); o.w = fmaxf(acc3, 0.f);
  float* d = a.tmp + (((size_t)st * BB + b) * HIDC + oc) * HWN + (ty0 + ps) * 32 + tx0;
  *(float4*)d = o;
}

struct Dec2Args { const float* tmp; const float* w; const float* b;
                  float* dst0; float* dst1; long bstr; };

__global__ __launch_bounds__(256) void dec2_kernel(Dec2Args a) {
  const int tile = blockIdx.x, b = blockIdx.y, st = blockIdx.z;
  const int ty0 = (tile >> 1) * 16, tx0 = (tile & 1) * 16;
  const int py = threadIdx.x >> 4, px = threadIdx.x & 15;
  const int gy = ty0 + py, gx = tx0 + px;
  const float* ip = a.tmp + ((size_t)st * BB + b) * HIDC * HWN;
  float acc = a.b[0];
  for (int ic = 0; ic < 64; ++ic) {
#pragma unroll
    for (int ky = 0; ky < 3; ++ky) {
      int yy = gy + ky - 1;
      if ((unsigned)yy >= 32u) continue;
#pragma unroll
      for (int kx = 0; kx < 3; ++kx) {
        int xx = gx + kx - 1;
        if ((unsigned)xx >= 32u) continue;
        acc += a.w[ic * 9 + ky * 3 + kx] * ip[ic * HWN + yy * 32 + xx];
      }
    }
  }
  float* d = (st == 0 ? a.dst0 : a.dst1);
  d[(size_t)b * a.bstr + gy * 32 + gx] = acc;
}

// ---------------------------------------------------------------- host
extern "C" void kernel_launch(void* const* d_in, const int* in_sizes, int n_in,
                              void* d_out, int out_size, void* d_ws, size_t ws_size,
                              hipStream_t stream) {
  (void)in_sizes; (void)n_in; (void)out_size; (void)ws_size;
  const float* x1_seq = (const float*)d_in[0];
  const float* x2_seq = (const float*)d_in[1];
  const float* c1w[2] = {(const float*)d_in[2], (const float*)d_in[4]};
  const float* c1b[2] = {(const float*)d_in[3], (const float*)d_in[5]};
  const float* c2w[2] = {(const float*)d_in[6], (const float*)d_in[8]};
  const float* c2b[2] = {(const float*)d_in[7], (const float*)d_in[9]};
  const float* sah_w = (const float*)d_in[10]; const float* sah_b = (const float*)d_in[11];
  const float* sac_w = (const float*)d_in[12]; const float* sac_b = (const float*)d_in[13];
  const float* cah_w = (const float*)d_in[14]; const float* cah_b = (const float*)d_in[15];
  const float* cac_w = (const float*)d_in[16]; const float* cac_b = (const float*)d_in[17];
  const float* dw1 = (const float*)d_in[18]; const float* db1 = (const float*)d_in[19];
  const float* dw2 = (const float*)d_in[20]; const float* db2 = (const float*)d_in[21];
  float* out = (float*)d_out;
  float* ws = (float*)d_ws;

  const size_t SPL = (size_t)BB * HIDC * HWN;   // 131072 floats
  float* h1s = ws;                // [2][SPL] states per layer
  float* c1s = h1s + 2 * SPL;
  float* h2s = c1s + 2 * SPL;
  float* c2s = h2s + 2 * SPL;
  float* hc1 = c2s + 2 * SPL;     // cell outputs
  float* cc1 = hc1 + SPL;
  float* hc2 = cc1 + SPL;
  float* cc2 = hc2 + SPL;
  float* hs1 = cc2 + SPL;         // self-attn outputs
  float* cs1 = hs1 + SPL;
  float* hs2 = cs1 + SPL;
  float* cs2 = hs2 + SPL;
  float* Qb  = cs2 + SPL;         // [4][B][1024][64]
  float* Kb  = Qb + 4 * SPL;
  float* Vb  = Kb + 4 * SPL;
  float* dtmp = Vb + 4 * SPL;     // [2][B][64][1024]

  hipMemsetAsync(ws, 0, 8 * SPL * sizeof(float), stream);  // zero states

  const dim3 blk(256);

  auto attn_stage = [&](const float* q0, const float* q1, const float* q2, const float* q3,
                        const float* k0, const float* k1, const float* k2, const float* k3,
                        const float* wh, const float* bh, const float* wc, const float* bc,
                        float* o0, float* o1, float* o2, float* o3) {
    QkvArgs qa;
    qa.xq[0]=q0; qa.xq[1]=q1; qa.xq[2]=q2; qa.xq[3]=q3;
    qa.xkv[0]=k0; qa.xkv[1]=k1; qa.xkv[2]=k2; qa.xkv[3]=k3;
    qa.w[0]=wh; qa.w[1]=wc; qa.w[2]=wh; qa.w[3]=wc;
    qa.bias[0]=bh; qa.bias[1]=bc; qa.bias[2]=bh; qa.bias[3]=bc;
    qa.Q=Qb; qa.K=Kb; qa.V=Vb;
    qkv_kernel<<<dim3(4, BB, 12), blk, 0, stream>>>(qa);
    AttnArgs aa;
    aa.xq[0]=q0; aa.xq[1]=q1; aa.xq[2]=q2; aa.xq[3]=q3;
    aa.out[0]=o0; aa.out[1]=o1; aa.out[2]=o2; aa.out[3]=o3;
    aa.Q=Qb; aa.K=Kb; aa.V=Vb;
    attn_kernel<<<dim3(32, BB, 4), blk, 0, stream>>>(aa);
  };

  auto decode = [&](long off1, long off2, long bstr) {
    Dec1Args d1; d1.in[0] = h1s + SPL; d1.in[1] = h2s + SPL;
    d1.w = dw1; d1.b = db1; d1.tmp = dtmp;
    dec1_kernel<<<dim3(64, BB, 2), blk, 0, stream>>>(d1);
    Dec2Args d2; d2.tmp = dtmp; d2.w = dw2; d2.b = db2;
    d2.dst0 = out + off1; d2.dst1 = out + off2; d2.bstr = bstr;
    dec2_kernel<<<dim3(4, BB, 2), blk, 0, stream>>>(d2);
  };

  // 6 steps: 3 warm + 3 future-consuming (last future step's state is never read)
  for (int s = 0; s < 6; ++s) {
    const float *x1, *x2; long xbs;
    if (s < 3) { x1 = x1_seq + s * HWN; x2 = x2_seq + s * HWN; xbs = 3 * HWN; }
    else       { x1 = out + (s - 3) * HWN; x2 = out + 8192 + (s - 3) * HWN; xbs = 4 * HWN; }

    for (int l = 0; l < 2; ++l) {
      if (l == 1) { x1 = h1s; x2 = h2s; xbs = (long)HIDC * HWN; }  // layer-0 state (this step)
      CellArgs ca;
      ca.x[0] = x1; ca.x[1] = x2; ca.xbs = xbs;
      ca.h[0] = h1s + l * SPL; ca.h[1] = h2s + l * SPL;
      ca.c[0] = c1s + l * SPL; ca.c[1] = c2s + l * SPL;
      ca.w[0] = c1w[l]; ca.w[1] = c2w[l];
      ca.bias[0] = c1b[l]; ca.bias[1] = c2b[l];
      ca.ho[0] = hc1; ca.ho[1] = hc2; ca.co[0] = cc1; ca.co[1] = cc2;
      if (l == 0) cell_kernel<1><<<dim3(64, BB, 2), blk, 0, stream>>>(ca);
      else        cell_kernel<64><<<dim3(64, BB, 2), blk, 0, stream>>>(ca);

      // self-attention: (h1,h1,sah) (c1,c1,sac) (h2,h2,sah) (c2,c2,sac)
      attn_stage(hc1, cc1, hc2, cc2,
                 hc1, cc1, hc2, cc2,
                 sah_w + l * 12288, sah_b + l * 192,
                 sac_w + l * 12288, sac_b + l * 192,
                 hs1, cs1, hs2, cs2);
      // cross-attention: (h1,h2,cah) (c1,c2,cac) (h2,tag_h1,cah) (c2,tag_c1,cac)
      attn_stage(hs1, cs1, hs2, cs2,
                 hs2, cs2, hs1, cs1,
                 cah_w + l * 12288, cah_b + l * 192,
                 cac_w + l * 12288, cac_b + l * 192,
                 h1s + l * SPL, c1s + l * SPL, h2s + l * SPL, c2s + l * SPL);
    }

    if (s == 0)      decode(16384,        20480,        2048);  // warm slot 0
    else if (s == 1) decode(16384 + 1024, 20480 + 1024, 2048);  // warm slot 1
    else             decode((s - 2) * HWN, 8192 + (s - 2) * HWN, 4096); // future slots
  }
}

// Round 4
// 3231.366 us; speedup vs baseline: 1.1544x; 1.1544x over previous
//
#include <hip/hip_runtime.h>
#include <math.h>

#define BB 2
#define HIDC 64
#define HWN 1024

// ---------------------------------------------------------------- ConvLSTM cell
struct CellArgs {
  const float* x[2]; long xbs;
  const float* h[2]; const float* c[2];
  const float* w[2]; const float* bias[2];
  float* ho[2]; float* co[2];
};

template<int CX>
__global__ __launch_bounds__(512) void cell_kernel(CellArgs a) {
  constexpr int CT = CX + HIDC;          // total input channels (concat x,h)
  constexpr int CH = (CT + 1) / 2;       // ic split point
  __shared__ float sIn[CT * 48];         // [CT][6][8] padded rows
  __shared__ float sGa[256 * 17];        // gates partial, ic-half 0
  __shared__ float sGb[256 * 17];        // gates partial, ic-half 1
  const int tile = blockIdx.x;           // 64 tiles of 4x4
  const int b = blockIdx.y;
  const int st = blockIdx.z;
  const int ty0 = (tile >> 3) << 2, tx0 = (tile & 7) << 2;
  const float* xp = a.x[st] + (size_t)b * a.xbs;
  const float* hp = a.h[st] + (size_t)b * HIDC * HWN;

  for (int idx = threadIdx.x; idx < CT * 36; idx += 512) {
    int ic = idx / 36, pos = idx - ic * 36;
    int iy = pos / 6, ix = pos - iy * 6;
    int gy = ty0 - 1 + iy, gx = tx0 - 1 + ix;
    float v = 0.f;
    if ((unsigned)gy < 32u && (unsigned)gx < 32u) {
      v = (ic < CX) ? xp[ic * HWN + gy * 32 + gx]
                    : hp[(ic - CX) * HWN + gy * 32 + gx];
    }
    sIn[ic * 48 + iy * 8 + ix] = v;
  }
  __syncthreads();

  const int oc = threadIdx.x & 255;      // gate channel
  const int hh = threadIdx.x >> 8;       // ic half
  const int icb = hh ? CH : 0, ice = hh ? CT : CH;
  float acc[16];
#pragma unroll
  for (int p = 0; p < 16; ++p) acc[p] = 0.f;
  const float* wp = a.w[st] + (size_t)oc * CT * 9;
  for (int ic = icb; ic < ice; ++ic) {
    float w9[9];
#pragma unroll
    for (int t = 0; t < 9; ++t) w9[t] = wp[ic * 9 + t];
    float in[36];
#pragma unroll
    for (int iy = 0; iy < 6; ++iy) {
      float4 v4 = *(const float4*)&sIn[ic * 48 + iy * 8];
      float2 v2 = *(const float2*)&sIn[ic * 48 + iy * 8 + 4];
      in[iy * 6 + 0] = v4.x; in[iy * 6 + 1] = v4.y; in[iy * 6 + 2] = v4.z;
      in[iy * 6 + 3] = v4.w; in[iy * 6 + 4] = v2.x; in[iy * 6 + 5] = v2.y;
    }
#pragma unroll
    for (int ky = 0; ky < 3; ++ky)
#pragma unroll
      for (int kx = 0; kx < 3; ++kx) {
        const float wv = w9[ky * 3 + kx];
#pragma unroll
        for (int py = 0; py < 4; ++py)
#pragma unroll
          for (int px = 0; px < 4; ++px)
            acc[py * 4 + px] += wv * in[(py + ky) * 6 + (px + kx)];
      }
  }
  float* sGh = hh ? sGb : sGa;
#pragma unroll
  for (int p = 0; p < 16; ++p) sGh[oc * 17 + p] = acc[p];
  __syncthreads();

  const float* cp = a.c[st] + (size_t)b * HIDC * HWN;
  float* hop = a.ho[st] + (size_t)b * HIDC * HWN;
  float* cop = a.co[st] + (size_t)b * HIDC * HWN;
  const float* bias = a.bias[st];
  for (int idx = threadIdx.x; idx < HIDC * 16; idx += 512) {
    int hc = idx >> 4, p = idx & 15;
    float gi = sGa[hc * 17 + p]         + sGb[hc * 17 + p]         + bias[hc];
    float gf = sGa[(hc + 64) * 17 + p]  + sGb[(hc + 64) * 17 + p]  + bias[hc + 64];
    float go = sGa[(hc + 128) * 17 + p] + sGb[(hc + 128) * 17 + p] + bias[hc + 128];
    float gg = sGa[(hc + 192) * 17 + p] + sGb[(hc + 192) * 17 + p] + bias[hc + 192];
    gi = 1.f / (1.f + expf(-gi));
    gf = 1.f / (1.f + expf(-gf));
    go = 1.f / (1.f + expf(-go));
    gg = tanhf(gg);
    int off = hc * HWN + (ty0 + (p >> 2)) * 32 + tx0 + (p & 3);
    float cn = gf * cp[off] + gi * gg;
    cop[off] = cn;
    hop[off] = go * tanhf(cn);
  }
}

// ---------------------------------------------------------------- QKV (1x1 convs)
struct QkvArgs {
  const float* xq[4]; const float* xkv[4];
  const float* w[4]; const float* bias[4];
  float* Q; float* K; float* V;          // each [4][B][1024][64]
};

__global__ __launch_bounds__(256) void qkv_kernel(QkvArgs a) {
  __shared__ float sWt[64 * 68];         // [c][o] transposed, pad 68
  const int ptile = blockIdx.x, b = blockIdx.y;
  const int attn = blockIdx.z / 3, proj = blockIdx.z % 3;
  const float* x = (proj == 0 ? a.xq[attn] : a.xkv[attn]) + (size_t)b * HIDC * HWN;
  const float* w = a.w[attn] + proj * 64 * 64;
  const float* bias = a.bias[attn] + proj * 64;
  float* dst = (proj == 0 ? a.Q : (proj == 1 ? a.K : a.V)) +
               ((size_t)attn * BB + b) * HWN * HIDC;
  for (int i = threadIdx.x; i < 4096; i += 256) {
    int o = i >> 6, c = i & 63;
    sWt[c * 68 + o] = w[i];
  }
  __syncthreads();
  const int og = threadIdx.x & 3, pq = threadIdx.x >> 2;
  const int p0 = ptile * 128 + pq * 2;
  float acc[2][16];
#pragma unroll
  for (int k = 0; k < 16; ++k) {
    float bv = bias[og * 16 + k];
    acc[0][k] = bv; acc[1][k] = bv;
  }
  for (int c = 0; c < 64; ++c) {
    float2 xv = *(const float2*)&x[c * HWN + p0];
#pragma unroll
    for (int k = 0; k < 16; k += 4) {
      float4 wv = *(const float4*)&sWt[c * 68 + og * 16 + k];
      acc[0][k+0] += xv.x*wv.x; acc[0][k+1] += xv.x*wv.y; acc[0][k+2] += xv.x*wv.z; acc[0][k+3] += xv.x*wv.w;
      acc[1][k+0] += xv.y*wv.x; acc[1][k+1] += xv.y*wv.y; acc[1][k+2] += xv.y*wv.z; acc[1][k+3] += xv.y*wv.w;
    }
  }
#pragma unroll
  for (int px = 0; px < 2; ++px) {
    float* d = dst + (size_t)(p0 + px) * HIDC + og * 16;
#pragma unroll
    for (int k = 0; k < 16; k += 4) {
      float4 v; v.x = acc[px][k]; v.y = acc[px][k+1]; v.z = acc[px][k+2]; v.w = acc[px][k+3];
      *(float4*)&d[k] = v;
    }
  }
}

// ---------------------------------------------------------------- flash attention
struct AttnArgs {
  const float* xq[4]; float* out[4];
  const float* Q; const float* K; const float* V;
};

__global__ __launch_bounds__(256) void attn_kernel(AttnArgs a) {
  __shared__ float sQt[64 * 36];   // [c][r] pad 36 (scaled by 1/8)
  __shared__ float sKt[64 * 68];   // [c][j] pad 68
  __shared__ float sV [64 * 68];   // [j][c] pad 68
  __shared__ float sPt[64 * 36];   // [j][r] pad 36
  const int qt = blockIdx.x, b = blockIdx.y, at = blockIdx.z;
  const size_t base = ((size_t)at * BB + b) * HWN * HIDC;
  const float* Qp = a.Q + base + (size_t)qt * 32 * HIDC;
  const float* Kp = a.K + base;
  const float* Vp = a.V + base;
  const int tid = threadIdx.x;
  {
    int r = tid >> 3, c0 = (tid & 7) * 8;
    const float* q = Qp + r * HIDC + c0;
#pragma unroll
    for (int k = 0; k < 8; k += 4) {
      float4 v = *(const float4*)&q[k];
      sQt[(c0 + k + 0) * 36 + r] = v.x * 0.125f;
      sQt[(c0 + k + 1) * 36 + r] = v.y * 0.125f;
      sQt[(c0 + k + 2) * 36 + r] = v.z * 0.125f;
      sQt[(c0 + k + 3) * 36 + r] = v.w * 0.125f;
    }
  }
  const int tc = tid & 15, tr = tid >> 4;
  const int r0 = tr * 2, j0 = tc * 4;
  const int sj = tid >> 2, scs = (tid & 3) * 16;   // staging coords
  float m0 = -1e30f, m1 = -1e30f, l0 = 0.f, l1 = 0.f;
  float o00=0,o01=0,o02=0,o03=0,o10=0,o11=0,o12=0,o13=0;

  // prefetch kt=0 into registers (T14 async-stage split)
  float4 kr[4], vr[4];
  {
    const float* kp = Kp + (size_t)sj * HIDC + scs;
    const float* vp = Vp + (size_t)sj * HIDC + scs;
#pragma unroll
    for (int q = 0; q < 4; ++q) {
      kr[q] = *(const float4*)&kp[q * 4];
      vr[q] = *(const float4*)&vp[q * 4];
    }
  }

  for (int kt = 0; kt < 16; ++kt) {
    __syncthreads();                     // previous PV readers done
    {
#pragma unroll
      for (int q = 0; q < 4; ++q) {
        sKt[(scs + q * 4 + 0) * 68 + sj] = kr[q].x;
        sKt[(scs + q * 4 + 1) * 68 + sj] = kr[q].y;
        sKt[(scs + q * 4 + 2) * 68 + sj] = kr[q].z;
        sKt[(scs + q * 4 + 3) * 68 + sj] = kr[q].w;
        *(float4*)&sV[sj * 68 + scs + q * 4] = vr[q];
      }
    }
    __syncthreads();
    if (kt < 15) {                        // issue next-tile loads; latency hides under compute
      const float* kp = Kp + (size_t)((kt + 1) * 64 + sj) * HIDC + scs;
      const float* vp = Vp + (size_t)((kt + 1) * 64 + sj) * HIDC + scs;
#pragma unroll
      for (int q = 0; q < 4; ++q) {
        kr[q] = *(const float4*)&kp[q * 4];
        vr[q] = *(const float4*)&vp[q * 4];
      }
    }
    float s00=0,s01=0,s02=0,s03=0,s10=0,s11=0,s12=0,s13=0;
#pragma unroll 4
    for (int c = 0; c < 64; ++c) {
      float2 qv = *(const float2*)&sQt[c * 36 + r0];
      float4 kv = *(const float4*)&sKt[c * 68 + j0];
      s00 += qv.x*kv.x; s01 += qv.x*kv.y; s02 += qv.x*kv.z; s03 += qv.x*kv.w;
      s10 += qv.y*kv.x; s11 += qv.y*kv.y; s12 += qv.y*kv.z; s13 += qv.y*kv.w;
    }
    float mt0 = fmaxf(fmaxf(s00, s01), fmaxf(s02, s03));
    float mt1 = fmaxf(fmaxf(s10, s11), fmaxf(s12, s13));
#pragma unroll
    for (int d = 1; d < 16; d <<= 1) {
      mt0 = fmaxf(mt0, __shfl_xor(mt0, d));
      mt1 = fmaxf(mt1, __shfl_xor(mt1, d));
    }
    float mn0 = fmaxf(m0, mt0), mn1 = fmaxf(m1, mt1);
    float al0 = __expf(m0 - mn0), al1 = __expf(m1 - mn1);
    s00 = __expf(s00 - mn0); s01 = __expf(s01 - mn0);
    s02 = __expf(s02 - mn0); s03 = __expf(s03 - mn0);
    s10 = __expf(s10 - mn1); s11 = __expf(s11 - mn1);
    s12 = __expf(s12 - mn1); s13 = __expf(s13 - mn1);
    float ps0 = s00 + s01 + s02 + s03, ps1 = s10 + s11 + s12 + s13;
#pragma unroll
    for (int d = 1; d < 16; d <<= 1) {
      ps0 += __shfl_xor(ps0, d);
      ps1 += __shfl_xor(ps1, d);
    }
    l0 = l0 * al0 + ps0; l1 = l1 * al1 + ps1;
    m0 = mn0; m1 = mn1;
    o00*=al0; o01*=al0; o02*=al0; o03*=al0;
    o10*=al1; o11*=al1; o12*=al1; o13*=al1;
    float2 pv;
    pv.x=s00; pv.y=s10; *(float2*)&sPt[(j0+0)*36 + r0] = pv;
    pv.x=s01; pv.y=s11; *(float2*)&sPt[(j0+1)*36 + r0] = pv;
    pv.x=s02; pv.y=s12; *(float2*)&sPt[(j0+2)*36 + r0] = pv;
    pv.x=s03; pv.y=s13; *(float2*)&sPt[(j0+3)*36 + r0] = pv;
    __syncthreads();
#pragma unroll 4
    for (int j = 0; j < 64; ++j) {
      float2 pj = *(const float2*)&sPt[j * 36 + r0];
      float4 vv = *(const float4*)&sV[j * 68 + j0];
      o00 += pj.x*vv.x; o01 += pj.x*vv.y; o02 += pj.x*vv.z; o03 += pj.x*vv.w;
      o10 += pj.y*vv.x; o11 += pj.y*vv.y; o12 += pj.y*vv.z; o13 += pj.y*vv.w;
    }
  }
  const float* xq = a.xq[at] + (size_t)b * HIDC * HWN;
  float* op = a.out[at] + (size_t)b * HIDC * HWN;
  const int p0 = qt * 32 + r0;
  const float inv0 = 1.f / l0, inv1 = 1.f / l1;
  op[(j0+0)*HWN + p0]   = o00*inv0 + xq[(j0+0)*HWN + p0];
  op[(j0+1)*HWN + p0]   = o01*inv0 + xq[(j0+1)*HWN + p0];
  op[(j0+2)*HWN + p0]   = o02*inv0 + xq[(j0+2)*HWN + p0];
  op[(j0+3)*HWN + p0]   = o03*inv0 + xq[(j0+3)*HWN + p0];
  op[(j0+0)*HWN + p0+1] = o10*inv1 + xq[(j0+0)*HWN + p0+1];
  op[(j0+1)*HWN + p0+1] = o11*inv1 + xq[(j0+1)*HWN + p0+1];
  op[(j0+2)*HWN + p0+1] = o12*inv1 + xq[(j0+2)*HWN + p0+1];
  op[(j0+3)*HWN + p0+1] = o13*inv1 + xq[(j0+3)*HWN + p0+1];
}

// ---------------------------------------------------------------- decoder
struct Dec1Args { const float* in[2]; const float* w; const float* b; float* tmp; };

__global__ __launch_bounds__(512) void dec1_kernel(Dec1Args a) {
  __shared__ float sIn[64 * 48];
  __shared__ float sHa[64 * 17];
  __shared__ float sHb[64 * 17];
  const int tile = blockIdx.x, b = blockIdx.y, st = blockIdx.z;
  const int ty0 = (tile >> 3) << 2, tx0 = (tile & 7) << 2;
  const float* ip = a.in[st] + (size_t)b * HIDC * HWN;
  for (int idx = threadIdx.x; idx < 64 * 36; idx += 512) {
    int ic = idx / 36, pos = idx - ic * 36;
    int iy = pos / 6, ix = pos - iy * 6;
    int gy = ty0 - 1 + iy, gx = tx0 - 1 + ix;
    float v = 0.f;
    if ((unsigned)gy < 32u && (unsigned)gx < 32u) v = ip[ic * HWN + gy * 32 + gx];
    sIn[ic * 48 + iy * 8 + ix] = v;
  }
  __syncthreads();
  const int oc = threadIdx.x & 63, ps = (threadIdx.x >> 6) & 3;
  const int hh = threadIdx.x >> 8;
  const int icb = hh * 32, ice = icb + 32;
  float acc0 = 0.f, acc1 = 0.f, acc2 = 0.f, acc3 = 0.f;
  const float* wp = a.w + (size_t)oc * 64 * 9;
  for (int ic = icb; ic < ice; ++ic) {
    float in[18];
#pragma unroll
    for (int ry = 0; ry < 3; ++ry) {
      float4 v4 = *(const float4*)&sIn[ic * 48 + (ps + ry) * 8];
      float2 v2 = *(const float2*)&sIn[ic * 48 + (ps + ry) * 8 + 4];
      in[ry*6+0]=v4.x; in[ry*6+1]=v4.y; in[ry*6+2]=v4.z; in[ry*6+3]=v4.w;
      in[ry*6+4]=v2.x; in[ry*6+5]=v2.y;
    }
#pragma unroll
    for (int ky = 0; ky < 3; ++ky)
#pragma unroll
      for (int kx = 0; kx < 3; ++kx) {
        float wv = wp[ic * 9 + ky * 3 + kx];
        acc0 += wv * in[ky * 6 + kx + 0];
        acc1 += wv * in[ky * 6 + kx + 1];
        acc2 += wv * in[ky * 6 + kx + 2];
        acc3 += wv * in[ky * 6 + kx + 3];
      }
  }
  float* sH = hh ? sHb : sHa;
  sH[oc * 17 + ps * 4 + 0] = acc0;
  sH[oc * 17 + ps * 4 + 1] = acc1;
  sH[oc * 17 + ps * 4 + 2] = acc2;
  sH[oc * 17 + ps * 4 + 3] = acc3;
  __syncthreads();
  float* dst = a.tmp + ((size_t)st * BB + b) * HIDC * HWN;
  for (int idx = threadIdx.x; idx < 1024; idx += 512) {
    int oc2 = idx >> 4, p = idx & 15;
    float v = sHa[oc2 * 17 + p] + sHb[oc2 * 17 + p] + a.b[oc2];
    v = fmaxf(v, 0.f);
    dst[(size_t)oc2 * HWN + (ty0 + (p >> 2)) * 32 + tx0 + (p & 3)] = v;
  }
}

struct Dec2Args { const float* tmp; const float* w; const float* b;
                  float* dst0; float* dst1; long bstr; };

__global__ __launch_bounds__(256) void dec2_kernel(Dec2Args a) {
  __shared__ float sIn[64 * 48];
  __shared__ float sW[64 * 9];
  const int tile = blockIdx.x, b = blockIdx.y, st = blockIdx.z;
  const int ty0 = (tile >> 3) << 2, tx0 = (tile & 7) << 2;
  const float* ip = a.tmp + ((size_t)st * BB + b) * HIDC * HWN;
  for (int idx = threadIdx.x; idx < 64 * 36; idx += 256) {
    int ic = idx / 36, pos = idx - ic * 36;
    int iy = pos / 6, ix = pos - iy * 6;
    int gy = ty0 - 1 + iy, gx = tx0 - 1 + ix;
    float v = 0.f;
    if ((unsigned)gy < 32u && (unsigned)gx < 32u) v = ip[ic * HWN + gy * 32 + gx];
    sIn[ic * 48 + iy * 8 + ix] = v;
  }
  for (int idx = threadIdx.x; idx < 576; idx += 256) sW[idx] = a.w[idx];
  __syncthreads();
  const int px = threadIdx.x >> 4, icg = threadIdx.x & 15;
  const int py = px >> 2, pxx = px & 3;
  float acc = 0.f;
#pragma unroll
  for (int i = 0; i < 4; ++i) {
    int ic = icg * 4 + i;
    const float* row = &sIn[ic * 48];
    const float* wv = &sW[ic * 9];
#pragma unroll
    for (int ky = 0; ky < 3; ++ky)
#pragma unroll
      for (int kx = 0; kx < 3; ++kx)
        acc += wv[ky * 3 + kx] * row[(py + ky) * 8 + pxx + kx];
  }
#pragma unroll
  for (int d = 1; d < 16; d <<= 1) acc += __shfl_xor(acc, d);
  if (icg == 0) {
    float* d = (st == 0 ? a.dst0 : a.dst1);
    d[(size_t)b * a.bstr + (ty0 + py) * 32 + tx0 + pxx] = acc + a.b[0];
  }
}

// ---------------------------------------------------------------- host
extern "C" void kernel_launch(void* const* d_in, const int* in_sizes, int n_in,
                              void* d_out, int out_size, void* d_ws, size_t ws_size,
                              hipStream_t stream) {
  (void)in_sizes; (void)n_in; (void)out_size; (void)ws_size;
  const float* x1_seq = (const float*)d_in[0];
  const float* x2_seq = (const float*)d_in[1];
  const float* c1w[2] = {(const float*)d_in[2], (const float*)d_in[4]};
  const float* c1b[2] = {(const float*)d_in[3], (const float*)d_in[5]};
  const float* c2w[2] = {(const float*)d_in[6], (const float*)d_in[8]};
  const float* c2b[2] = {(const float*)d_in[7], (const float*)d_in[9]};
  const float* sah_w = (const float*)d_in[10]; const float* sah_b = (const float*)d_in[11];
  const float* sac_w = (const float*)d_in[12]; const float* sac_b = (const float*)d_in[13];
  const float* cah_w = (const float*)d_in[14]; const float* cah_b = (const float*)d_in[15];
  const float* cac_w = (const float*)d_in[16]; const float* cac_b = (const float*)d_in[17];
  const float* dw1 = (const float*)d_in[18]; const float* db1 = (const float*)d_in[19];
  const float* dw2 = (const float*)d_in[20]; const float* db2 = (const float*)d_in[21];
  float* out = (float*)d_out;
  float* ws = (float*)d_ws;

  const size_t SPL = (size_t)BB * HIDC * HWN;   // 131072 floats
  float* h1s = ws;                // [2][SPL] states per layer
  float* c1s = h1s + 2 * SPL;
  float* h2s = c1s + 2 * SPL;
  float* c2s = h2s + 2 * SPL;
  float* hc1 = c2s + 2 * SPL;     // cell outputs
  float* cc1 = hc1 + SPL;
  float* hc2 = cc1 + SPL;
  float* cc2 = hc2 + SPL;
  float* hs1 = cc2 + SPL;         // self-attn outputs
  float* cs1 = hs1 + SPL;
  float* hs2 = cs1 + SPL;
  float* cs2 = hs2 + SPL;
  float* Qb  = cs2 + SPL;         // [4][B][1024][64]
  float* Kb  = Qb + 4 * SPL;
  float* Vb  = Kb + 4 * SPL;
  float* dtmp = Vb + 4 * SPL;     // [2][B][64][1024]

  hipMemsetAsync(ws, 0, 8 * SPL * sizeof(float), stream);  // zero states

  const dim3 blk(256);
  const dim3 blk2(512);

  auto attn_stage = [&](const float* q0, const float* q1, const float* q2, const float* q3,
                        const float* k0, const float* k1, const float* k2, const float* k3,
                        const float* wh, const float* bh, const float* wc, const float* bc,
                        float* o0, float* o1, float* o2, float* o3) {
    QkvArgs qa;
    qa.xq[0]=q0; qa.xq[1]=q1; qa.xq[2]=q2; qa.xq[3]=q3;
    qa.xkv[0]=k0; qa.xkv[1]=k1; qa.xkv[2]=k2; qa.xkv[3]=k3;
    qa.w[0]=wh; qa.w[1]=wc; qa.w[2]=wh; qa.w[3]=wc;
    qa.bias[0]=bh; qa.bias[1]=bc; qa.bias[2]=bh; qa.bias[3]=bc;
    qa.Q=Qb; qa.K=Kb; qa.V=Vb;
    qkv_kernel<<<dim3(8, BB, 12), blk, 0, stream>>>(qa);
    AttnArgs aa;
    aa.xq[0]=q0; aa.xq[1]=q1; aa.xq[2]=q2; aa.xq[3]=q3;
    aa.out[0]=o0; aa.out[1]=o1; aa.out[2]=o2; aa.out[3]=o3;
    aa.Q=Qb; aa.K=Kb; aa.V=Vb;
    attn_kernel<<<dim3(32, BB, 4), blk, 0, stream>>>(aa);
  };

  auto decode = [&](long off1, long off2, long bstr) {
    Dec1Args d1; d1.in[0] = h1s + SPL; d1.in[1] = h2s + SPL;
    d1.w = dw1; d1.b = db1; d1.tmp = dtmp;
    dec1_kernel<<<dim3(64, BB, 2), blk2, 0, stream>>>(d1);
    Dec2Args d2; d2.tmp = dtmp; d2.w = dw2; d2.b = db2;
    d2.dst0 = out + off1; d2.dst1 = out + off2; d2.bstr = bstr;
    dec2_kernel<<<dim3(64, BB, 2), blk, 0, stream>>>(d2);
  };

  // 6 steps: 3 warm + 3 future-consuming (last future step's state is never read)
  for (int s = 0; s < 6; ++s) {
    const float *x1, *x2; long xbs;
    if (s < 3) { x1 = x1_seq + s * HWN; x2 = x2_seq + s * HWN; xbs = 3 * HWN; }
    else       { x1 = out + (s - 3) * HWN; x2 = out + 8192 + (s - 3) * HWN; xbs = 4 * HWN; }

    for (int l = 0; l < 2; ++l) {
      if (l == 1) { x1 = h1s; x2 = h2s; xbs = (long)HIDC * HWN; }  // layer-0 state (this step)
      CellArgs ca;
      ca.x[0] = x1; ca.x[1] = x2; ca.xbs = xbs;
      ca.h[0] = h1s + l * SPL; ca.h[1] = h2s + l * SPL;
      ca.c[0] = c1s + l * SPL; ca.c[1] = c2s + l * SPL;
      ca.w[0] = c1w[l]; ca.w[1] = c2w[l];
      ca.bias[0] = c1b[l]; ca.bias[1] = c2b[l];
      ca.ho[0] = hc1; ca.ho[1] = hc2; ca.co[0] = cc1; ca.co[1] = cc2;
      if (l == 0) cell_kernel<1><<<dim3(64, BB, 2), blk2, 0, stream>>>(ca);
      else        cell_kernel<64><<<dim3(64, BB, 2), blk2, 0, stream>>>(ca);

      // self-attention: (h1,h1,sah) (c1,c1,sac) (h2,h2,sah) (c2,c2,sac)
      attn_stage(hc1, cc1, hc2, cc2,
                 hc1, cc1, hc2, cc2,
                 sah_w + l * 12288, sah_b + l * 192,
                 sac_w + l * 12288, sac_b + l * 192,
                 hs1, cs1, hs2, cs2);
      // cross-attention: (h1,h2,cah) (c1,c2,cac) (h2,tag_h1,cah) (c2,tag_c1,cac)
      attn_stage(hs1, cs1, hs2, cs2,
                 hs2, cs2, hs1, cs1,
                 cah_w + l * 12288, cah_b + l * 192,
                 cac_w + l * 12288, cac_b + l * 192,
                 h1s + l * SPL, c1s + l * SPL, h2s + l * SPL, c2s + l * SPL);
    }

    if (s == 0)      decode(16384,        20480,        2048);  // warm slot 0
    else if (s == 1) decode(16384 + 1024, 20480 + 1024, 2048);  // warm slot 1
    else             decode((s - 2) * HWN, 8192 + (s - 2) * HWN, 4096); // future slots
  }
}

// Round 6
// 2587.609 us; speedup vs baseline: 1.4416x; 1.2488x over previous
//
#include <hip/hip_runtime.h>
#include <math.h>

#define BB 2
#define HIDC 64
#define HWN 1024

// ---------------------------------------------------------------- ConvLSTM cell
struct CellArgs {
  const float* x[2]; long xbs;
  const float* h[2]; const float* c[2];
  const float* w[2]; const float* bias[2];
  float* ho[2]; float* co[2];
};

template<int CX>
__global__ __launch_bounds__(512) void cell_kernel(CellArgs a) {
  constexpr int CT = CX + HIDC;          // total input channels (concat x,h)
  constexpr int CH = (CT + 1) / 2;       // ic split point
  __shared__ float sIn[CT * 48];         // [CT][6][8] padded rows
  __shared__ float sGa[256 * 17];        // gates partial, ic-half 0
  __shared__ float sGb[256 * 17];        // gates partial, ic-half 1
  const int tile = blockIdx.x;           // 64 tiles of 4x4
  const int b = blockIdx.y;
  const int st = blockIdx.z;
  const int ty0 = (tile >> 3) << 2, tx0 = (tile & 7) << 2;
  const float* xp = a.x[st] + (size_t)b * a.xbs;
  const float* hp = a.h[st] + (size_t)b * HIDC * HWN;

  for (int idx = threadIdx.x; idx < CT * 36; idx += 512) {
    int ic = idx / 36, pos = idx - ic * 36;
    int iy = pos / 6, ix = pos - iy * 6;
    int gy = ty0 - 1 + iy, gx = tx0 - 1 + ix;
    float v = 0.f;
    if ((unsigned)gy < 32u && (unsigned)gx < 32u) {
      v = (ic < CX) ? xp[ic * HWN + gy * 32 + gx]
                    : hp[(ic - CX) * HWN + gy * 32 + gx];
    }
    sIn[ic * 48 + iy * 8 + ix] = v;
  }
  __syncthreads();

  const int oc = threadIdx.x & 255;      // gate channel
  const int hh = threadIdx.x >> 8;       // ic half
  const int icb = hh ? CH : 0, ice = hh ? CT : CH;
  float acc[16];
#pragma unroll
  for (int p = 0; p < 16; ++p) acc[p] = 0.f;
  const float* wp = a.w[st] + (size_t)oc * CT * 9;
  for (int ic = icb; ic < ice; ++ic) {
    float w9[9];
#pragma unroll
    for (int t = 0; t < 9; ++t) w9[t] = wp[ic * 9 + t];
    float in[36];
#pragma unroll
    for (int iy = 0; iy < 6; ++iy) {
      float4 v4 = *(const float4*)&sIn[ic * 48 + iy * 8];
      float2 v2 = *(const float2*)&sIn[ic * 48 + iy * 8 + 4];
      in[iy * 6 + 0] = v4.x; in[iy * 6 + 1] = v4.y; in[iy * 6 + 2] = v4.z;
      in[iy * 6 + 3] = v4.w; in[iy * 6 + 4] = v2.x; in[iy * 6 + 5] = v2.y;
    }
#pragma unroll
    for (int ky = 0; ky < 3; ++ky)
#pragma unroll
      for (int kx = 0; kx < 3; ++kx) {
        const float wv = w9[ky * 3 + kx];
#pragma unroll
        for (int py = 0; py < 4; ++py)
#pragma unroll
          for (int px = 0; px < 4; ++px)
            acc[py * 4 + px] += wv * in[(py + ky) * 6 + (px + kx)];
      }
  }
  float* sGh = hh ? sGb : sGa;
#pragma unroll
  for (int p = 0; p < 16; ++p) sGh[oc * 17 + p] = acc[p];
  __syncthreads();

  const float* cp = a.c[st] + (size_t)b * HIDC * HWN;
  float* hop = a.ho[st] + (size_t)b * HIDC * HWN;
  float* cop = a.co[st] + (size_t)b * HIDC * HWN;
  const float* bias = a.bias[st];
  for (int idx = threadIdx.x; idx < HIDC * 16; idx += 512) {
    int hc = idx >> 4, p = idx & 15;
    float gi = sGa[hc * 17 + p]         + sGb[hc * 17 + p]         + bias[hc];
    float gf = sGa[(hc + 64) * 17 + p]  + sGb[(hc + 64) * 17 + p]  + bias[hc + 64];
    float go = sGa[(hc + 128) * 17 + p] + sGb[(hc + 128) * 17 + p] + bias[hc + 128];
    float gg = sGa[(hc + 192) * 17 + p] + sGb[(hc + 192) * 17 + p] + bias[hc + 192];
    gi = 1.f / (1.f + expf(-gi));
    gf = 1.f / (1.f + expf(-gf));
    go = 1.f / (1.f + expf(-go));
    gg = tanhf(gg);
    int off = hc * HWN + (ty0 + (p >> 2)) * 32 + tx0 + (p & 3);
    float cn = gf * cp[off] + gi * gg;
    cop[off] = cn;
    hop[off] = go * tanhf(cn);
  }
}

// ---------------------------------------------------------------- QKV (1x1 convs)
struct QkvArgs {
  const float* xq[4]; const float* xkv[4];
  const float* w[4]; const float* bias[4];
  float* Q; float* K; float* V;          // each [4][B][1024][64]
};

__global__ __launch_bounds__(256) void qkv_kernel(QkvArgs a) {
  __shared__ float sWt[64 * 68];         // [c][o] transposed, pad 68
  const int ptile = blockIdx.x, b = blockIdx.y;
  const int attn = blockIdx.z / 3, proj = blockIdx.z % 3;
  const float* x = (proj == 0 ? a.xq[attn] : a.xkv[attn]) + (size_t)b * HIDC * HWN;
  const float* w = a.w[attn] + proj * 64 * 64;
  const float* bias = a.bias[attn] + proj * 64;
  float* dst = (proj == 0 ? a.Q : (proj == 1 ? a.K : a.V)) +
               ((size_t)attn * BB + b) * HWN * HIDC;
  for (int i = threadIdx.x; i < 4096; i += 256) {
    int o = i >> 6, c = i & 63;
    sWt[c * 68 + o] = w[i];
  }
  __syncthreads();
  const int og = threadIdx.x & 3, pq = threadIdx.x >> 2;
  const int p0 = ptile * 128 + pq * 2;
  float acc[2][16];
#pragma unroll
  for (int k = 0; k < 16; ++k) {
    float bv = bias[og * 16 + k];
    acc[0][k] = bv; acc[1][k] = bv;
  }
  for (int c = 0; c < 64; ++c) {
    float2 xv = *(const float2*)&x[c * HWN + p0];
#pragma unroll
    for (int k = 0; k < 16; k += 4) {
      float4 wv = *(const float4*)&sWt[c * 68 + og * 16 + k];
      acc[0][k+0] += xv.x*wv.x; acc[0][k+1] += xv.x*wv.y; acc[0][k+2] += xv.x*wv.z; acc[0][k+3] += xv.x*wv.w;
      acc[1][k+0] += xv.y*wv.x; acc[1][k+1] += xv.y*wv.y; acc[1][k+2] += xv.y*wv.z; acc[1][k+3] += xv.y*wv.w;
    }
  }
#pragma unroll
  for (int px = 0; px < 2; ++px) {
    float* d = dst + (size_t)(p0 + px) * HIDC + og * 16;
#pragma unroll
    for (int k = 0; k < 16; k += 4) {
      float4 v; v.x = acc[px][k]; v.y = acc[px][k+1]; v.z = acc[px][k+2]; v.w = acc[px][k+3];
      *(float4*)&d[k] = v;
    }
  }
}

// ---------------------------------------------------------------- flash attention (KV-split partials)
struct AttnPArgs { const float* Q; const float* K; const float* V; float* pbuf; };

__global__ __launch_bounds__(256) void attn_part(AttnPArgs a) {
  __shared__ float sQt[64 * 36];   // [c][r] pad 36 (scaled by 1/8)
  __shared__ float sKt[64 * 68];   // [c][j] pad 68
  __shared__ float sV [64 * 68];   // [j][c] pad 68
  __shared__ float sPt[64 * 36];   // [j][r] pad 36
  const int qt = blockIdx.x >> 2, ks = blockIdx.x & 3;   // q-tile, kv-split
  const int b = blockIdx.y, at = blockIdx.z;
  const size_t base = ((size_t)at * BB + b) * HWN * HIDC;
  const float* Qp = a.Q + base + (size_t)qt * 32 * HIDC;
  const float* Kp = a.K + base;
  const float* Vp = a.V + base;
  const int tid = threadIdx.x;
  {
    int r = tid >> 3, c0 = (tid & 7) * 8;
    const float* q = Qp + r * HIDC + c0;
#pragma unroll
    for (int k = 0; k < 8; k += 4) {
      float4 v = *(const float4*)&q[k];
      sQt[(c0 + k + 0) * 36 + r] = v.x * 0.125f;
      sQt[(c0 + k + 1) * 36 + r] = v.y * 0.125f;
      sQt[(c0 + k + 2) * 36 + r] = v.z * 0.125f;
      sQt[(c0 + k + 3) * 36 + r] = v.w * 0.125f;
    }
  }
  const int tc = tid & 15, tr = tid >> 4;
  const int r0 = tr * 2, j0 = tc * 4;
  // K staging: row kj = tid&63 spans whole wave -> write banks (i*4+kj)%32 = 2-way (free)
  const int kj = tid & 63, kch = (tid >> 6) * 16;
  const int sj = tid >> 2, scs = (tid & 3) * 16;
  float m0 = -1e30f, m1 = -1e30f, l0 = 0.f, l1 = 0.f;
  float o00=0,o01=0,o02=0,o03=0,o10=0,o11=0,o12=0,o13=0;

  const int ktb = ks * 4;
  float4 kr[4], vr[4];
  {
    const float* kp = Kp + (size_t)(ktb * 64 + kj) * HIDC + kch;
    const float* vp = Vp + (size_t)(ktb * 64 + sj) * HIDC + scs;
#pragma unroll
    for (int q = 0; q < 4; ++q) {
      kr[q] = *(const float4*)&kp[q * 4];
      vr[q] = *(const float4*)&vp[q * 4];
    }
  }

  for (int kk = 0; kk < 4; ++kk) {
    __syncthreads();                     // previous PV readers done
#pragma unroll
    for (int q = 0; q < 4; ++q) {
      sKt[(kch + q * 4 + 0) * 68 + kj] = kr[q].x;
      sKt[(kch + q * 4 + 1) * 68 + kj] = kr[q].y;
      sKt[(kch + q * 4 + 2) * 68 + kj] = kr[q].z;
      sKt[(kch + q * 4 + 3) * 68 + kj] = kr[q].w;
      *(float4*)&sV[sj * 68 + scs + q * 4] = vr[q];
    }
    __syncthreads();
    if (kk < 3) {                        // prefetch next tile; hides under compute
      const float* kp = Kp + (size_t)((ktb + kk + 1) * 64 + kj) * HIDC + kch;
      const float* vp = Vp + (size_t)((ktb + kk + 1) * 64 + sj) * HIDC + scs;
#pragma unroll
      for (int q = 0; q < 4; ++q) {
        kr[q] = *(const float4*)&kp[q * 4];
        vr[q] = *(const float4*)&vp[q * 4];
      }
    }
    float s00=0,s01=0,s02=0,s03=0,s10=0,s11=0,s12=0,s13=0;
#pragma unroll 4
    for (int c = 0; c < 64; ++c) {
      float2 qv = *(const float2*)&sQt[c * 36 + r0];
      float4 kv = *(const float4*)&sKt[c * 68 + j0];
      s00 += qv.x*kv.x; s01 += qv.x*kv.y; s02 += qv.x*kv.z; s03 += qv.x*kv.w;
      s10 += qv.y*kv.x; s11 += qv.y*kv.y; s12 += qv.y*kv.z; s13 += qv.y*kv.w;
    }
    float mt0 = fmaxf(fmaxf(s00, s01), fmaxf(s02, s03));
    float mt1 = fmaxf(fmaxf(s10, s11), fmaxf(s12, s13));
#pragma unroll
    for (int d = 1; d < 16; d <<= 1) {
      mt0 = fmaxf(mt0, __shfl_xor(mt0, d));
      mt1 = fmaxf(mt1, __shfl_xor(mt1, d));
    }
    float mn0 = fmaxf(m0, mt0), mn1 = fmaxf(m1, mt1);
    float al0 = __expf(m0 - mn0), al1 = __expf(m1 - mn1);
    s00 = __expf(s00 - mn0); s01 = __expf(s01 - mn0);
    s02 = __expf(s02 - mn0); s03 = __expf(s03 - mn0);
    s10 = __expf(s10 - mn1); s11 = __expf(s11 - mn1);
    s12 = __expf(s12 - mn1); s13 = __expf(s13 - mn1);
    float ps0 = s00 + s01 + s02 + s03, ps1 = s10 + s11 + s12 + s13;
#pragma unroll
    for (int d = 1; d < 16; d <<= 1) {
      ps0 += __shfl_xor(ps0, d);
      ps1 += __shfl_xor(ps1, d);
    }
    l0 = l0 * al0 + ps0; l1 = l1 * al1 + ps1;
    m0 = mn0; m1 = mn1;
    o00*=al0; o01*=al0; o02*=al0; o03*=al0;
    o10*=al1; o11*=al1; o12*=al1; o13*=al1;
    float2 pv;
    pv.x=s00; pv.y=s10; *(float2*)&sPt[(j0+0)*36 + r0] = pv;
    pv.x=s01; pv.y=s11; *(float2*)&sPt[(j0+1)*36 + r0] = pv;
    pv.x=s02; pv.y=s12; *(float2*)&sPt[(j0+2)*36 + r0] = pv;
    pv.x=s03; pv.y=s13; *(float2*)&sPt[(j0+3)*36 + r0] = pv;
    __syncthreads();
#pragma unroll 4
    for (int j = 0; j < 64; ++j) {
      float2 pj = *(const float2*)&sPt[j * 36 + r0];
      float4 vv = *(const float4*)&sV[j * 68 + j0];
      o00 += pj.x*vv.x; o01 += pj.x*vv.y; o02 += pj.x*vv.z; o03 += pj.x*vv.w;
      o10 += pj.y*vv.x; o11 += pj.y*vv.y; o12 += pj.y*vv.z; o13 += pj.y*vv.w;
    }
  }
  // partial record: [32x64 o (unnormalized)] [32 m] [32 l] = 2112 floats
  float* pb = a.pbuf + ((((size_t)at * BB + b) * 32 + qt) * 4 + ks) * 2112;
  float4 w0; w0.x=o00; w0.y=o01; w0.z=o02; w0.w=o03;
  float4 w1; w1.x=o10; w1.y=o11; w1.z=o12; w1.w=o13;
  *(float4*)&pb[r0 * 64 + j0] = w0;
  *(float4*)&pb[(r0 + 1) * 64 + j0] = w1;
  if (tc == 0) {
    pb[2048 + r0] = m0; pb[2048 + r0 + 1] = m1;
    pb[2080 + r0] = l0; pb[2080 + r0 + 1] = l1;
  }
}

struct AttnMArgs { const float* pbuf; const float* xq[4]; float* out[4]; };

__global__ __launch_bounds__(256) void attn_merge(AttnMArgs a) {
  const int qt = blockIdx.x, b = blockIdx.y, at = blockIdx.z;
  const float* pb = a.pbuf + (((size_t)at * BB + b) * 32 + qt) * 4 * 2112;
  const int c = threadIdx.x >> 2;          // channel 0..63
  const int rq = (threadIdx.x & 3) * 8;    // row base
  const float* xq = a.xq[at] + (size_t)b * HIDC * HWN;
  float* op = a.out[at] + (size_t)b * HIDC * HWN;
  const int p0 = qt * 32 + rq;
  float res[8];
#pragma unroll
  for (int rr = 0; rr < 8; ++rr) {
    int r = rq + rr;
    float mm0 = pb[2048 + r],            mm1 = pb[2112 + 2048 + r];
    float mm2 = pb[2*2112 + 2048 + r],   mm3 = pb[3*2112 + 2048 + r];
    float M = fmaxf(fmaxf(mm0, mm1), fmaxf(mm2, mm3));
    float w0 = __expf(mm0 - M), w1 = __expf(mm1 - M);
    float w2 = __expf(mm2 - M), w3 = __expf(mm3 - M);
    float L = pb[2080 + r]*w0 + pb[2112 + 2080 + r]*w1 +
              pb[2*2112 + 2080 + r]*w2 + pb[3*2112 + 2080 + r]*w3;
    float acc = pb[r*64 + c]*w0 + pb[2112 + r*64 + c]*w1 +
                pb[2*2112 + r*64 + c]*w2 + pb[3*2112 + r*64 + c]*w3;
    res[rr] = acc / L;
  }
  float4 x0 = *(const float4*)&xq[(size_t)c * HWN + p0];
  float4 x1 = *(const float4*)&xq[(size_t)c * HWN + p0 + 4];
  float4 o0, o1;
  o0.x = res[0] + x0.x; o0.y = res[1] + x0.y; o0.z = res[2] + x0.z; o0.w = res[3] + x0.w;
  o1.x = res[4] + x1.x; o1.y = res[5] + x1.y; o1.z = res[6] + x1.z; o1.w = res[7] + x1.w;
  *(float4*)&op[(size_t)c * HWN + p0] = o0;
  *(float4*)&op[(size_t)c * HWN + p0 + 4] = o1;
}

// ---------------------------------------------------------------- decoder
struct Dec1Args { const float* in[2]; const float* w; const float* b; float* tmp; };

__global__ __launch_bounds__(512) void dec1_kernel(Dec1Args a) {
  __shared__ float sIn[64 * 48];
  __shared__ float sHa[64 * 17];
  __shared__ float sHb[64 * 17];
  const int tile = blockIdx.x, b = blockIdx.y, st = blockIdx.z;
  const int ty0 = (tile >> 3) << 2, tx0 = (tile & 7) << 2;
  const float* ip = a.in[st] + (size_t)b * HIDC * HWN;
  for (int idx = threadIdx.x; idx < 64 * 36; idx += 512) {
    int ic = idx / 36, pos = idx - ic * 36;
    int iy = pos / 6, ix = pos - iy * 6;
    int gy = ty0 - 1 + iy, gx = tx0 - 1 + ix;
    float v = 0.f;
    if ((unsigned)gy < 32u && (unsigned)gx < 32u) v = ip[ic * HWN + gy * 32 + gx];
    sIn[ic * 48 + iy * 8 + ix] = v;
  }
  __syncthreads();
  const int oc = threadIdx.x & 63, ps = (threadIdx.x >> 6) & 3;
  const int hh = threadIdx.x >> 8;
  const int icb = hh * 32, ice = icb + 32;
  float acc0 = 0.f, acc1 = 0.f, acc2 = 0.f, acc3 = 0.f;
  const float* wp = a.w + (size_t)oc * 64 * 9;
  for (int ic = icb; ic < ice; ++ic) {
    float in[18];
#pragma unroll
    for (int ry = 0; ry < 3; ++ry) {
      float4 v4 = *(const float4*)&sIn[ic * 48 + (ps + ry) * 8];
      float2 v2 = *(const float2*)&sIn[ic * 48 + (ps + ry) * 8 + 4];
      in[ry*6+0]=v4.x; in[ry*6+1]=v4.y; in[ry*6+2]=v4.z; in[ry*6+3]=v4.w;
      in[ry*6+4]=v2.x; in[ry*6+5]=v2.y;
    }
#pragma unroll
    for (int ky = 0; ky < 3; ++ky)
#pragma unroll
      for (int kx = 0; kx < 3; ++kx) {
        float wv = wp[ic * 9 + ky * 3 + kx];
        acc0 += wv * in[ky * 6 + kx + 0];
        acc1 += wv * in[ky * 6 + kx + 1];
        acc2 += wv * in[ky * 6 + kx + 2];
        acc3 += wv * in[ky * 6 + kx + 3];
      }
  }
  float* sH = hh ? sHb : sHa;
  sH[oc * 17 + ps * 4 + 0] = acc0;
  sH[oc * 17 + ps * 4 + 1] = acc1;
  sH[oc * 17 + ps * 4 + 2] = acc2;
  sH[oc * 17 + ps * 4 + 3] = acc3;
  __syncthreads();
  float* dst = a.tmp + ((size_t)st * BB + b) * HIDC * HWN;
  for (int idx = threadIdx.x; idx < 1024; idx += 512) {
    int oc2 = idx >> 4, p = idx & 15;
    float v = sHa[oc2 * 17 + p] + sHb[oc2 * 17 + p] + a.b[oc2];
    v = fmaxf(v, 0.f);
    dst[(size_t)oc2 * HWN + (ty0 + (p >> 2)) * 32 + tx0 + (p & 3)] = v;
  }
}

struct Dec2Args { const float* tmp; const float* w; const float* b;
                  float* dst0; float* dst1; long bstr; };

__global__ __launch_bounds__(256) void dec2_kernel(Dec2Args a) {
  __shared__ float sIn[64 * 48];
  __shared__ float sW[64 * 9];
  const int tile = blockIdx.x, b = blockIdx.y, st = blockIdx.z;
  const int ty0 = (tile >> 3) << 2, tx0 = (tile & 7) << 2;
  const float* ip = a.tmp + ((size_t)st * BB + b) * HIDC * HWN;
  for (int idx = threadIdx.x; idx < 64 * 36; idx += 256) {
    int ic = idx / 36, pos = idx - ic * 36;
    int iy = pos / 6, ix = pos - iy * 6;
    int gy = ty0 - 1 + iy, gx = tx0 - 1 + ix;
    float v = 0.f;
    if ((unsigned)gy < 32u && (unsigned)gx < 32u) v = ip[ic * HWN + gy * 32 + gx];
    sIn[ic * 48 + iy * 8 + ix] = v;
  }
  for (int idx = threadIdx.x; idx < 576; idx += 256) sW[idx] = a.w[idx];
  __syncthreads();
  const int px = threadIdx.x >> 4, icg = threadIdx.x & 15;
  const int py = px >> 2, pxx = px & 3;
  float acc = 0.f;
#pragma unroll
  for (int i = 0; i < 4; ++i) {
    int ic = icg * 4 + i;
    const float* row = &sIn[ic * 48];
    const float* wv = &sW[ic * 9];
#pragma unroll
    for (int ky = 0; ky < 3; ++ky)
#pragma unroll
      for (int kx = 0; kx < 3; ++kx)
        acc += wv[ky * 3 + kx] * row[(py + ky) * 8 + pxx + kx];
  }
#pragma unroll
  for (int d = 1; d < 16; d <<= 1) acc += __shfl_xor(acc, d);
  if (icg == 0) {
    float* d = (st == 0 ? a.dst0 : a.dst1);
    d[(size_t)b * a.bstr + (ty0 + py) * 32 + tx0 + pxx] = acc + a.b[0];
  }
}

// ---------------------------------------------------------------- host
extern "C" void kernel_launch(void* const* d_in, const int* in_sizes, int n_in,
                              void* d_out, int out_size, void* d_ws, size_t ws_size,
                              hipStream_t stream) {
  (void)in_sizes; (void)n_in; (void)out_size; (void)ws_size;
  const float* x1_seq = (const float*)d_in[0];
  const float* x2_seq = (const float*)d_in[1];
  const float* c1w[2] = {(const float*)d_in[2], (const float*)d_in[4]};
  const float* c1b[2] = {(const float*)d_in[3], (const float*)d_in[5]};
  const float* c2w[2] = {(const float*)d_in[6], (const float*)d_in[8]};
  const float* c2b[2] = {(const float*)d_in[7], (const float*)d_in[9]};
  const float* sah_w = (const float*)d_in[10]; const float* sah_b = (const float*)d_in[11];
  const float* sac_w = (const float*)d_in[12]; const float* sac_b = (const float*)d_in[13];
  const float* cah_w = (const float*)d_in[14]; const float* cah_b = (const float*)d_in[15];
  const float* cac_w = (const float*)d_in[16]; const float* cac_b = (const float*)d_in[17];
  const float* dw1 = (const float*)d_in[18]; const float* db1 = (const float*)d_in[19];
  const float* dw2 = (const float*)d_in[20]; const float* db2 = (const float*)d_in[21];
  float* out = (float*)d_out;
  float* ws = (float*)d_ws;

  const size_t SPL = (size_t)BB * HIDC * HWN;   // 131072 floats
  float* h1s = ws;                // [2][SPL] states per layer
  float* c1s = h1s + 2 * SPL;
  float* h2s = c1s + 2 * SPL;
  float* c2s = h2s + 2 * SPL;
  float* hc1 = c2s + 2 * SPL;     // cell outputs
  float* cc1 = hc1 + SPL;
  float* hc2 = cc1 + SPL;
  float* cc2 = hc2 + SPL;
  float* hs1 = cc2 + SPL;         // self-attn outputs
  float* cs1 = hs1 + SPL;
  float* hs2 = cs1 + SPL;
  float* cs2 = hs2 + SPL;
  float* Qb  = cs2 + SPL;         // [4][B][1024][64]
  float* Kb  = Qb + 4 * SPL;
  float* Vb  = Kb + 4 * SPL;
  float* dtmp = Vb + 4 * SPL;     // [2][B][64][1024]
  float* pbuf = dtmp + 2 * SPL;   // [4at][B][32qt][4ks][2112]  (~8.7 MB)

  hipMemsetAsync(ws, 0, 8 * SPL * sizeof(float), stream);  // zero states

  const dim3 blk(256);
  const dim3 blk2(512);

  auto attn_stage = [&](const float* q0, const float* q1, const float* q2, const float* q3,
                        const float* k0, const float* k1, const float* k2, const float* k3,
                        const float* wh, const float* bh, const float* wc, const float* bc,
                        float* o0, float* o1, float* o2, float* o3) {
    QkvArgs qa;
    qa.xq[0]=q0; qa.xq[1]=q1; qa.xq[2]=q2; qa.xq[3]=q3;
    qa.xkv[0]=k0; qa.xkv[1]=k1; qa.xkv[2]=k2; qa.xkv[3]=k3;
    qa.w[0]=wh; qa.w[1]=wc; qa.w[2]=wh; qa.w[3]=wc;
    qa.bias[0]=bh; qa.bias[1]=bc; qa.bias[2]=bh; qa.bias[3]=bc;
    qa.Q=Qb; qa.K=Kb; qa.V=Vb;
    qkv_kernel<<<dim3(8, BB, 12), blk, 0, stream>>>(qa);
    AttnPArgs ap; ap.Q=Qb; ap.K=Kb; ap.V=Vb; ap.pbuf=pbuf;
    attn_part<<<dim3(128, BB, 4), blk, 0, stream>>>(ap);
    AttnMArgs am; am.pbuf=pbuf;
    am.xq[0]=q0; am.xq[1]=q1; am.xq[2]=q2; am.xq[3]=q3;
    am.out[0]=o0; am.out[1]=o1; am.out[2]=o2; am.out[3]=o3;
    attn_merge<<<dim3(32, BB, 4), blk, 0, stream>>>(am);
  };

  auto decode = [&](long off1, long off2, long bstr) {
    Dec1Args d1; d1.in[0] = h1s + SPL; d1.in[1] = h2s + SPL;
    d1.w = dw1; d1.b = db1; d1.tmp = dtmp;
    dec1_kernel<<<dim3(64, BB, 2), blk2, 0, stream>>>(d1);
    Dec2Args d2; d2.tmp = dtmp; d2.w = dw2; d2.b = db2;
    d2.dst0 = out + off1; d2.dst1 = out + off2; d2.bstr = bstr;
    dec2_kernel<<<dim3(64, BB, 2), blk, 0, stream>>>(d2);
  };

  // 6 steps: 3 warm + 3 future-consuming (last future step's state is never read)
  for (int s = 0; s < 6; ++s) {
    const float *x1, *x2; long xbs;
    if (s < 3) { x1 = x1_seq + s * HWN; x2 = x2_seq + s * HWN; xbs = 3 * HWN; }
    else       { x1 = out + (s - 3) * HWN; x2 = out + 8192 + (s - 3) * HWN; xbs = 4 * HWN; }

    for (int l = 0; l < 2; ++l) {
      if (l == 1) { x1 = h1s; x2 = h2s; xbs = (long)HIDC * HWN; }  // layer-0 state (this step)
      CellArgs ca;
      ca.x[0] = x1; ca.x[1] = x2; ca.xbs = xbs;
      ca.h[0] = h1s + l * SPL; ca.h[1] = h2s + l * SPL;
      ca.c[0] = c1s + l * SPL; ca.c[1] = c2s + l * SPL;
      ca.w[0] = c1w[l]; ca.w[1] = c2w[l];
      ca.bias[0] = c1b[l]; ca.bias[1] = c2b[l];
      ca.ho[0] = hc1; ca.ho[1] = hc2; ca.co[0] = cc1; ca.co[1] = cc2;
      if (l == 0) cell_kernel<1><<<dim3(64, BB, 2), blk2, 0, stream>>>(ca);
      else        cell_kernel<64><<<dim3(64, BB, 2), blk2, 0, stream>>>(ca);

      // self-attention: (h1,h1,sah) (c1,c1,sac) (h2,h2,sah) (c2,c2,sac)
      attn_stage(hc1, cc1, hc2, cc2,
                 hc1, cc1, hc2, cc2,
                 sah_w + l * 12288, sah_b + l * 192,
                 sac_w + l * 12288, sac_b + l * 192,
                 hs1, cs1, hs2, cs2);
      // cross-attention: (h1,h2,cah) (c1,c2,cac) (h2,tag_h1,cah) (c2,tag_c1,cac)
      attn_stage(hs1, cs1, hs2, cs2,
                 hs2, cs2, hs1, cs1,
                 cah_w + l * 12288, cah_b + l * 192,
                 cac_w + l * 12288, cac_b + l * 192,
                 h1s + l * SPL, c1s + l * SPL, h2s + l * SPL, c2s + l * SPL);
    }

    if (s == 0)      decode(16384,        20480,        2048);  // warm slot 0
    else if (s == 1) decode(16384 + 1024, 20480 + 1024, 2048);  // warm slot 1
    else             decode((s - 2) * HWN, 8192 + (s - 2) * HWN, 4096); // future slots
  }
}

// Round 7
// 2431.994 us; speedup vs baseline: 1.5338x; 1.0640x over previous
//
#include <hip/hip_runtime.h>
#include <math.h>

#define BB 2
#define HIDC 64
#define HWN 1024

// ---------------------------------------------------------------- weight transpose
// dst[arr] layout: [icn*9][ocn] ; src layout: [ocn][icn*9]
struct TWArgs { const float* src[5]; float* dst[5]; int icn9[5]; int osh[5]; };

__global__ __launch_bounds__(256) void transpose_w(TWArgs a) {
  const int arr = blockIdx.y;
  const int icn9 = a.icn9[arr], osh = a.osh[arr];
  const int ocn = 1 << osh;
  const float* s = a.src[arr];
  float* d = a.dst[arr];
  const int n = icn9 << osh;
  for (int i = blockIdx.x * 256 + threadIdx.x; i < n; i += gridDim.x * 256) {
    int oc = i & (ocn - 1), tt = i >> osh;
    d[i] = s[(size_t)oc * icn9 + tt];
  }
}

// ---------------------------------------------------------------- ConvLSTM cell
struct CellArgs {
  const float* x[2]; long xbs;
  const float* h[2]; const float* c[2];
  const float* w[2]; const float* bias[2];   // w = TRANSPOSED [ic*9+t][256]
  float* ho[2]; float* co[2];
};

template<int CX>
__global__ __launch_bounds__(512) void cell_kernel(CellArgs a) {
  constexpr int CT = CX + HIDC;          // total input channels (concat x,h)
  constexpr int CH = (CT + 1) / 2;       // ic split point
  __shared__ float sIn[CT * 48];         // [CT][6][8] padded rows
  __shared__ float sGa[256 * 17];        // gates partial, ic-half 0
  __shared__ float sGb[256 * 17];        // gates partial, ic-half 1
  const int tile = blockIdx.x;           // 64 tiles of 4x4
  const int b = blockIdx.y;
  const int st = blockIdx.z;
  const int ty0 = (tile >> 3) << 2, tx0 = (tile & 7) << 2;
  const float* xp = a.x[st] + (size_t)b * a.xbs;
  const float* hp = a.h[st] + (size_t)b * HIDC * HWN;

  for (int idx = threadIdx.x; idx < CT * 36; idx += 512) {
    int ic = idx / 36, pos = idx - ic * 36;
    int iy = pos / 6, ix = pos - iy * 6;
    int gy = ty0 - 1 + iy, gx = tx0 - 1 + ix;
    float v = 0.f;
    if ((unsigned)gy < 32u && (unsigned)gx < 32u) {
      v = (ic < CX) ? xp[ic * HWN + gy * 32 + gx]
                    : hp[(ic - CX) * HWN + gy * 32 + gx];
    }
    sIn[ic * 48 + iy * 8 + ix] = v;
  }
  __syncthreads();

  const int oc = threadIdx.x & 255;      // gate channel
  const int hh = threadIdx.x >> 8;       // ic half
  const int icb = hh ? CH : 0, ice = hh ? CT : CH;
  float acc[16];
#pragma unroll
  for (int p = 0; p < 16; ++p) acc[p] = 0.f;
  const float* wp = a.w[st];             // transposed: [(ic*9+t)*256 + oc]
  for (int ic = icb; ic < ice; ++ic) {
    float w9[9];
#pragma unroll
    for (int t = 0; t < 9; ++t) w9[t] = wp[(ic * 9 + t) * 256 + oc];   // coalesced
    float in[36];
#pragma unroll
    for (int iy = 0; iy < 6; ++iy) {
      float4 v4 = *(const float4*)&sIn[ic * 48 + iy * 8];
      float2 v2 = *(const float2*)&sIn[ic * 48 + iy * 8 + 4];
      in[iy * 6 + 0] = v4.x; in[iy * 6 + 1] = v4.y; in[iy * 6 + 2] = v4.z;
      in[iy * 6 + 3] = v4.w; in[iy * 6 + 4] = v2.x; in[iy * 6 + 5] = v2.y;
    }
#pragma unroll
    for (int ky = 0; ky < 3; ++ky)
#pragma unroll
      for (int kx = 0; kx < 3; ++kx) {
        const float wv = w9[ky * 3 + kx];
#pragma unroll
        for (int py = 0; py < 4; ++py)
#pragma unroll
          for (int px = 0; px < 4; ++px)
            acc[py * 4 + px] += wv * in[(py + ky) * 6 + (px + kx)];
      }
  }
  float* sGh = hh ? sGb : sGa;
#pragma unroll
  for (int p = 0; p < 16; ++p) sGh[oc * 17 + p] = acc[p];
  __syncthreads();

  const float* cp = a.c[st] + (size_t)b * HIDC * HWN;
  float* hop = a.ho[st] + (size_t)b * HIDC * HWN;
  float* cop = a.co[st] + (size_t)b * HIDC * HWN;
  const float* bias = a.bias[st];
  for (int idx = threadIdx.x; idx < HIDC * 16; idx += 512) {
    int hc = idx >> 4, p = idx & 15;
    float gi = sGa[hc * 17 + p]         + sGb[hc * 17 + p]         + bias[hc];
    float gf = sGa[(hc + 64) * 17 + p]  + sGb[(hc + 64) * 17 + p]  + bias[hc + 64];
    float go = sGa[(hc + 128) * 17 + p] + sGb[(hc + 128) * 17 + p] + bias[hc + 128];
    float gg = sGa[(hc + 192) * 17 + p] + sGb[(hc + 192) * 17 + p] + bias[hc + 192];
    gi = 1.f / (1.f + expf(-gi));
    gf = 1.f / (1.f + expf(-gf));
    go = 1.f / (1.f + expf(-go));
    gg = tanhf(gg);
    int off = hc * HWN + (ty0 + (p >> 2)) * 32 + tx0 + (p & 3);
    float cn = gf * cp[off] + gi * gg;
    cop[off] = cn;
    hop[off] = go * tanhf(cn);
  }
}

// ---------------------------------------------------------------- QKV (1x1 convs)
struct QkvArgs {
  const float* xq[4]; const float* xkv[4];
  const float* w[4]; const float* bias[4];
  float* Q; float* K; float* V;          // each [4][B][1024][64]
};

__global__ __launch_bounds__(256) void qkv_kernel(QkvArgs a) {
  __shared__ float sWt[64 * 68];         // [c][o] transposed, pad 68
  const int ptile = blockIdx.x, b = blockIdx.y;
  const int attn = blockIdx.z / 3, proj = blockIdx.z % 3;
  const float* x = (proj == 0 ? a.xq[attn] : a.xkv[attn]) + (size_t)b * HIDC * HWN;
  const float* w = a.w[attn] + proj * 64 * 64;
  const float* bias = a.bias[attn] + proj * 64;
  float* dst = (proj == 0 ? a.Q : (proj == 1 ? a.K : a.V)) +
               ((size_t)attn * BB + b) * HWN * HIDC;
  for (int i = threadIdx.x; i < 4096; i += 256) {
    int o = i >> 6, c = i & 63;
    sWt[c * 68 + o] = w[i];
  }
  __syncthreads();
  const int pq = threadIdx.x & 63, og = threadIdx.x >> 6;
  const int p0 = ptile * 64 + pq;        // lane-consecutive px -> coalesced x reads
  float acc[16];
#pragma unroll
  for (int k = 0; k < 16; ++k) acc[k] = bias[og * 16 + k];
  for (int c = 0; c < 64; ++c) {
    float xv = x[c * HWN + p0];
#pragma unroll
    for (int k = 0; k < 16; k += 4) {
      float4 wv = *(const float4*)&sWt[c * 68 + og * 16 + k];
      acc[k+0] += xv * wv.x; acc[k+1] += xv * wv.y;
      acc[k+2] += xv * wv.z; acc[k+3] += xv * wv.w;
    }
  }
  float* d = dst + (size_t)p0 * HIDC + og * 16;
#pragma unroll
  for (int k = 0; k < 16; k += 4) {
    float4 v; v.x = acc[k]; v.y = acc[k+1]; v.z = acc[k+2]; v.w = acc[k+3];
    *(float4*)&d[k] = v;
  }
}

// ---------------------------------------------------------------- flash attention (KV-split partials)
// QBLK=64 rows, 256 threads, 4x4 register tile, 64KB no-pad LDS + XOR swizzle.
struct AttnPArgs { const float* Q; const float* K; const float* V; float* pbuf; };

__global__ __launch_bounds__(256) void attn_part(AttnPArgs a) {
  __shared__ float sQt[64 * 64];   // [c][r], scaled by 1/8
  __shared__ float sKt[64 * 64];   // [c][j]
  __shared__ float sV [64 * 64];   // [j][c ^ (j&7)*4]
  __shared__ float sPt[64 * 64];   // [j][r ^ (j&7)*4]
  const int qt = blockIdx.x >> 2, ks = blockIdx.x & 3;
  const int b = blockIdx.y, at = blockIdx.z;
  const size_t base = ((size_t)at * BB + b) * HWN * HIDC;
  const float* Qp = a.Q + base + (size_t)qt * 64 * HIDC;
  const float* Kp = a.K + base;
  const float* Vp = a.V + base;
  const int tid = threadIdx.x;
  { // Q stage: row qr, ch-chunk qc0; scalar transpose writes (bank = qr%32, 2-way)
    const int qr = tid & 63, qc0 = (tid >> 6) * 16;
    const float* q = Qp + qr * HIDC + qc0;
#pragma unroll
    for (int k = 0; k < 16; k += 4) {
      float4 v = *(const float4*)&q[k];
      sQt[(qc0 + k + 0) * 64 + qr] = v.x * 0.125f;
      sQt[(qc0 + k + 1) * 64 + qr] = v.y * 0.125f;
      sQt[(qc0 + k + 2) * 64 + qr] = v.z * 0.125f;
      sQt[(qc0 + k + 3) * 64 + qr] = v.w * 0.125f;
    }
  }
  const int tc = tid & 15, tr = tid >> 4;
  const int j0 = tc * 4, r0 = tr * 4;
  const int kj = tid & 63, kch = (tid >> 6) * 16;   // K stage
  const int vj = tid >> 2, vc0 = (tid & 3) * 16;    // V stage
  float m[4], l[4], o[4][4];
#pragma unroll
  for (int i = 0; i < 4; ++i) {
    m[i] = -1e30f; l[i] = 0.f;
    o[i][0] = 0; o[i][1] = 0; o[i][2] = 0; o[i][3] = 0;
  }

  const int ktb = ks * 4;
  float4 kr[4], vr[4];
  {
    const float* kp = Kp + (size_t)(ktb * 64 + kj) * HIDC + kch;
    const float* vp = Vp + (size_t)(ktb * 64 + vj) * HIDC + vc0;
#pragma unroll
    for (int q2 = 0; q2 < 4; ++q2) {
      kr[q2] = *(const float4*)&kp[q2 * 4];
      vr[q2] = *(const float4*)&vp[q2 * 4];
    }
  }

  for (int kk = 0; kk < 4; ++kk) {
    __syncthreads();                     // prev PV readers done
#pragma unroll
    for (int q2 = 0; q2 < 4; ++q2) {
      sKt[(kch + q2 * 4 + 0) * 64 + kj] = kr[q2].x;   // bank kj%32: 2-way free
      sKt[(kch + q2 * 4 + 1) * 64 + kj] = kr[q2].y;
      sKt[(kch + q2 * 4 + 2) * 64 + kj] = kr[q2].z;
      sKt[(kch + q2 * 4 + 3) * 64 + kj] = kr[q2].w;
      int c = vc0 + q2 * 4;
      *(float4*)&sV[vj * 64 + (c ^ ((vj & 7) * 4))] = vr[q2];  // swizzled b128
    }
    __syncthreads();
    if (kk < 3) {                        // prefetch next tile
      const float* kp = Kp + (size_t)((ktb + kk + 1) * 64 + kj) * HIDC + kch;
      const float* vp = Vp + (size_t)((ktb + kk + 1) * 64 + vj) * HIDC + vc0;
#pragma unroll
      for (int q2 = 0; q2 < 4; ++q2) {
        kr[q2] = *(const float4*)&kp[q2 * 4];
        vr[q2] = *(const float4*)&vp[q2 * 4];
      }
    }
    // S = (Q/8) K^T : 4 rows x 4 cols per thread
    float s[4][4];
#pragma unroll
    for (int i = 0; i < 4; ++i) { s[i][0]=0; s[i][1]=0; s[i][2]=0; s[i][3]=0; }
#pragma unroll 4
    for (int c = 0; c < 64; ++c) {
      float4 q4 = *(const float4*)&sQt[c * 64 + r0];   // broadcast, conflict-free
      float4 k4 = *(const float4*)&sKt[c * 64 + j0];   // 2-way
      s[0][0]+=q4.x*k4.x; s[0][1]+=q4.x*k4.y; s[0][2]+=q4.x*k4.z; s[0][3]+=q4.x*k4.w;
      s[1][0]+=q4.y*k4.x; s[1][1]+=q4.y*k4.y; s[1][2]+=q4.y*k4.z; s[1][3]+=q4.y*k4.w;
      s[2][0]+=q4.z*k4.x; s[2][1]+=q4.z*k4.y; s[2][2]+=q4.z*k4.z; s[2][3]+=q4.z*k4.w;
      s[3][0]+=q4.w*k4.x; s[3][1]+=q4.w*k4.y; s[3][2]+=q4.w*k4.z; s[3][3]+=q4.w*k4.w;
    }
    // online softmax (row groups = 16 lanes, xor d<16)
    float mt[4];
#pragma unroll
    for (int i = 0; i < 4; ++i)
      mt[i] = fmaxf(fmaxf(s[i][0], s[i][1]), fmaxf(s[i][2], s[i][3]));
#pragma unroll
    for (int d = 1; d < 16; d <<= 1) {
#pragma unroll
      for (int i = 0; i < 4; ++i) mt[i] = fmaxf(mt[i], __shfl_xor(mt[i], d));
    }
    float al[4];
#pragma unroll
    for (int i = 0; i < 4; ++i) {
      float mn = fmaxf(m[i], mt[i]);
      al[i] = __expf(m[i] - mn);
      m[i] = mn;
      s[i][0] = __expf(s[i][0] - mn); s[i][1] = __expf(s[i][1] - mn);
      s[i][2] = __expf(s[i][2] - mn); s[i][3] = __expf(s[i][3] - mn);
    }
    float ps[4];
#pragma unroll
    for (int i = 0; i < 4; ++i) ps[i] = s[i][0] + s[i][1] + s[i][2] + s[i][3];
#pragma unroll
    for (int d = 1; d < 16; d <<= 1) {
#pragma unroll
      for (int i = 0; i < 4; ++i) ps[i] += __shfl_xor(ps[i], d);
    }
#pragma unroll
    for (int i = 0; i < 4; ++i) {
      l[i] = l[i] * al[i] + ps[i];
      o[i][0] *= al[i]; o[i][1] *= al[i]; o[i][2] *= al[i]; o[i][3] *= al[i];
    }
    // P write: swizzled b128 rows
#pragma unroll
    for (int jj = 0; jj < 4; ++jj) {
      int j = j0 + jj;
      float4 pv; pv.x = s[0][jj]; pv.y = s[1][jj]; pv.z = s[2][jj]; pv.w = s[3][jj];
      *(float4*)&sPt[j * 64 + (r0 ^ ((j & 7) * 4))] = pv;
    }
    __syncthreads();
    // PV: out cols j0..j0+3 (channels)
#pragma unroll 4
    for (int j = 0; j < 64; ++j) {
      float4 p4 = *(const float4*)&sPt[j * 64 + (r0 ^ ((j & 7) * 4))];  // broadcast
      float4 v4 = *(const float4*)&sV [j * 64 + (j0 ^ ((j & 7) * 4))];  // 2-way
      o[0][0]+=p4.x*v4.x; o[0][1]+=p4.x*v4.y; o[0][2]+=p4.x*v4.z; o[0][3]+=p4.x*v4.w;
      o[1][0]+=p4.y*v4.x; o[1][1]+=p4.y*v4.y; o[1][2]+=p4.y*v4.z; o[1][3]+=p4.y*v4.w;
      o[2][0]+=p4.z*v4.x; o[2][1]+=p4.z*v4.y; o[2][2]+=p4.z*v4.z; o[2][3]+=p4.z*v4.w;
      o[3][0]+=p4.w*v4.x; o[3][1]+=p4.w*v4.y; o[3][2]+=p4.w*v4.z; o[3][3]+=p4.w*v4.w;
    }
  }
  // partial record: [64x64 o (unnormalized)] [64 m] [64 l] = 4224 floats
  float* pb = a.pbuf + ((((size_t)at * BB + b) * 16 + qt) * 4 + ks) * 4224;
#pragma unroll
  for (int i = 0; i < 4; ++i) {
    float4 w; w.x = o[i][0]; w.y = o[i][1]; w.z = o[i][2]; w.w = o[i][3];
    *(float4*)&pb[(r0 + i) * 64 + j0] = w;
  }
  if (tc == 0) {
#pragma unroll
    for (int i = 0; i < 4; ++i) {
      pb[4096 + r0 + i] = m[i];
      pb[4160 + r0 + i] = l[i];
    }
  }
}

struct AttnMArgs { const float* pbuf; const float* xq[4]; float* out[4]; };

__global__ __launch_bounds__(256) void attn_merge(AttnMArgs a) {
  __shared__ float sW[4][64];
  __shared__ float sL[64];
  const int qt = blockIdx.x, b = blockIdx.y, at = blockIdx.z;
  const float* pb = a.pbuf + (((size_t)at * BB + b) * 16 + qt) * 4 * 4224;
  if (threadIdx.x < 64) {
    int r = threadIdx.x;
    float m0 = pb[4096 + r],          m1 = pb[4224 + 4096 + r];
    float m2 = pb[2*4224 + 4096 + r], m3 = pb[3*4224 + 4096 + r];
    float M = fmaxf(fmaxf(m0, m1), fmaxf(m2, m3));
    float w0 = __expf(m0 - M), w1 = __expf(m1 - M);
    float w2 = __expf(m2 - M), w3 = __expf(m3 - M);
    sW[0][r] = w0; sW[1][r] = w1; sW[2][r] = w2; sW[3][r] = w3;
    sL[r] = pb[4160 + r] * w0 + pb[4224 + 4160 + r] * w1 +
            pb[2*4224 + 4160 + r] * w2 + pb[3*4224 + 4160 + r] * w3;
  }
  __syncthreads();
  const int c = threadIdx.x >> 2, rg = (threadIdx.x & 3) * 16;
  const float* xq = a.xq[at] + (size_t)b * HIDC * HWN;
  float* op = a.out[at] + (size_t)b * HIDC * HWN;
  const int p0 = qt * 64 + rg;
#pragma unroll
  for (int rr4 = 0; rr4 < 16; rr4 += 4) {
    float rv[4];
#pragma unroll
    for (int k = 0; k < 4; ++k) {
      int r = rg + rr4 + k;
      float acc = pb[r*64 + c] * sW[0][r] + pb[4224 + r*64 + c] * sW[1][r]
                + pb[2*4224 + r*64 + c] * sW[2][r] + pb[3*4224 + r*64 + c] * sW[3][r];
      rv[k] = acc / sL[r];
    }
    float4 x4 = *(const float4*)&xq[(size_t)c * HWN + p0 + rr4];
    float4 res; res.x = rv[0] + x4.x; res.y = rv[1] + x4.y;
    res.z = rv[2] + x4.z; res.w = rv[3] + x4.w;
    *(float4*)&op[(size_t)c * HWN + p0 + rr4] = res;
  }
}

// ---------------------------------------------------------------- decoder
struct Dec1Args { const float* in[2]; const float* w; const float* b; float* tmp; };

__global__ __launch_bounds__(512) void dec1_kernel(Dec1Args a) {
  __shared__ float sIn[64 * 48];
  __shared__ float sHa[64 * 17];
  __shared__ float sHb[64 * 17];
  const int tile = blockIdx.x, b = blockIdx.y, st = blockIdx.z;
  const int ty0 = (tile >> 3) << 2, tx0 = (tile & 7) << 2;
  const float* ip = a.in[st] + (size_t)b * HIDC * HWN;
  for (int idx = threadIdx.x; idx < 64 * 36; idx += 512) {
    int ic = idx / 36, pos = idx - ic * 36;
    int iy = pos / 6, ix = pos - iy * 6;
    int gy = ty0 - 1 + iy, gx = tx0 - 1 + ix;
    float v = 0.f;
    if ((unsigned)gy < 32u && (unsigned)gx < 32u) v = ip[ic * HWN + gy * 32 + gx];
    sIn[ic * 48 + iy * 8 + ix] = v;
  }
  __syncthreads();
  const int oc = threadIdx.x & 63, ps = (threadIdx.x >> 6) & 3;
  const int hh = threadIdx.x >> 8;
  const int icb = hh * 32, ice = icb + 32;
  float acc0 = 0.f, acc1 = 0.f, acc2 = 0.f, acc3 = 0.f;
  const float* wp = a.w;                 // transposed [(ic*9+t)*64 + oc]
  for (int ic = icb; ic < ice; ++ic) {
    float w9[9];
#pragma unroll
    for (int t = 0; t < 9; ++t) w9[t] = wp[(ic * 9 + t) * 64 + oc];   // coalesced
    float in[18];
#pragma unroll
    for (int ry = 0; ry < 3; ++ry) {
      float4 v4 = *(const float4*)&sIn[ic * 48 + (ps + ry) * 8];
      float2 v2 = *(const float2*)&sIn[ic * 48 + (ps + ry) * 8 + 4];
      in[ry*6+0]=v4.x; in[ry*6+1]=v4.y; in[ry*6+2]=v4.z; in[ry*6+3]=v4.w;
      in[ry*6+4]=v2.x; in[ry*6+5]=v2.y;
    }
#pragma unroll
    for (int ky = 0; ky < 3; ++ky)
#pragma unroll
      for (int kx = 0; kx < 3; ++kx) {
        float wv = w9[ky * 3 + kx];
        acc0 += wv * in[ky * 6 + kx + 0];
        acc1 += wv * in[ky * 6 + kx + 1];
        acc2 += wv * in[ky * 6 + kx + 2];
        acc3 += wv * in[ky * 6 + kx + 3];
      }
  }
  float* sH = hh ? sHb : sHa;
  sH[oc * 17 + ps * 4 + 0] = acc0;
  sH[oc * 17 + ps * 4 + 1] = acc1;
  sH[oc * 17 + ps * 4 + 2] = acc2;
  sH[oc * 17 + ps * 4 + 3] = acc3;
  __syncthreads();
  float* dst = a.tmp + ((size_t)st * BB + b) * HIDC * HWN;
  for (int idx = threadIdx.x; idx < 1024; idx += 512) {
    int oc2 = idx >> 4, p = idx & 15;
    float v = sHa[oc2 * 17 + p] + sHb[oc2 * 17 + p] + a.b[oc2];
    v = fmaxf(v, 0.f);
    dst[(size_t)oc2 * HWN + (ty0 + (p >> 2)) * 32 + tx0 + (p & 3)] = v;
  }
}

struct Dec2Args { const float* tmp; const float* w; const float* b;
                  float* dst0; float* dst1; long bstr; };

__global__ __launch_bounds__(256) void dec2_kernel(Dec2Args a) {
  __shared__ float sIn[64 * 48];
  __shared__ float sW[64 * 9];
  const int tile = blockIdx.x, b = blockIdx.y, st = blockIdx.z;
  const int ty0 = (tile >> 3) << 2, tx0 = (tile & 7) << 2;
  const float* ip = a.tmp + ((size_t)st * BB + b) * HIDC * HWN;
  for (int idx = threadIdx.x; idx < 64 * 36; idx += 256) {
    int ic = idx / 36, pos = idx - ic * 36;
    int iy = pos / 6, ix = pos - iy * 6;
    int gy = ty0 - 1 + iy, gx = tx0 - 1 + ix;
    float v = 0.f;
    if ((unsigned)gy < 32u && (unsigned)gx < 32u) v = ip[ic * HWN + gy * 32 + gx];
    sIn[ic * 48 + iy * 8 + ix] = v;
  }
  for (int idx = threadIdx.x; idx < 576; idx += 256) sW[idx] = a.w[idx];
  __syncthreads();
  const int px = threadIdx.x >> 4, icg = threadIdx.x & 15;
  const int py = px >> 2, pxx = px & 3;
  float acc = 0.f;
#pragma unroll
  for (int i = 0; i < 4; ++i) {
    int ic = icg * 4 + i;
    const float* row = &sIn[ic * 48];
    const float* wv = &sW[ic * 9];
#pragma unroll
    for (int ky = 0; ky < 3; ++ky)
#pragma unroll
      for (int kx = 0; kx < 3; ++kx)
        acc += wv[ky * 3 + kx] * row[(py + ky) * 8 + pxx + kx];
  }
#pragma unroll
  for (int d = 1; d < 16; d <<= 1) acc += __shfl_xor(acc, d);
  if (icg == 0) {
    float* d = (st == 0 ? a.dst0 : a.dst1);
    d[(size_t)b * a.bstr + (ty0 + py) * 32 + tx0 + pxx] = acc + a.b[0];
  }
}

// ---------------------------------------------------------------- host
extern "C" void kernel_launch(void* const* d_in, const int* in_sizes, int n_in,
                              void* d_out, int out_size, void* d_ws, size_t ws_size,
                              hipStream_t stream) {
  (void)in_sizes; (void)n_in; (void)out_size; (void)ws_size;
  const float* x1_seq = (const float*)d_in[0];
  const float* x2_seq = (const float*)d_in[1];
  const float* c1w[2] = {(const float*)d_in[2], (const float*)d_in[4]};
  const float* c1b[2] = {(const float*)d_in[3], (const float*)d_in[5]};
  const float* c2w[2] = {(const float*)d_in[6], (const float*)d_in[8]};
  const float* c2b[2] = {(const float*)d_in[7], (const float*)d_in[9]};
  const float* sah_w = (const float*)d_in[10]; const float* sah_b = (const float*)d_in[11];
  const float* sac_w = (const float*)d_in[12]; const float* sac_b = (const float*)d_in[13];
  const float* cah_w = (const float*)d_in[14]; const float* cah_b = (const float*)d_in[15];
  const float* cac_w = (const float*)d_in[16]; const float* cac_b = (const float*)d_in[17];
  const float* dw1 = (const float*)d_in[18]; const float* db1 = (const float*)d_in[19];
  const float* dw2 = (const float*)d_in[20]; const float* db2 = (const float*)d_in[21];
  float* out = (float*)d_out;
  float* ws = (float*)d_ws;

  const size_t SPL = (size_t)BB * HIDC * HWN;   // 131072 floats
  float* h1s = ws;                // [2][SPL] states per layer
  float* c1s = h1s + 2 * SPL;
  float* h2s = c1s + 2 * SPL;
  float* c2s = h2s + 2 * SPL;
  float* hc1 = c2s + 2 * SPL;     // cell outputs
  float* cc1 = hc1 + SPL;
  float* hc2 = cc1 + SPL;
  float* cc2 = hc2 + SPL;
  float* hs1 = cc2 + SPL;         // self-attn outputs
  float* cs1 = hs1 + SPL;
  float* hs2 = cs1 + SPL;
  float* cs2 = hs2 + SPL;
  float* Qb  = cs2 + SPL;         // [4][B][1024][64]
  float* Kb  = Qb + 4 * SPL;
  float* Vb  = Kb + 4 * SPL;
  float* dtmp = Vb + 4 * SPL;     // [2][B][64][1024]
  float* pbuf = dtmp + 2 * SPL;   // [4at][B][16qt][4ks][4224]  (~8.7 MB)
  float* wt10 = pbuf + (size_t)4 * BB * 16 * 4 * 4224;   // transposed weights
  float* wt11 = wt10 + 585 * 256;
  float* wt20 = wt11 + 1152 * 256;
  float* wt21 = wt20 + 585 * 256;
  float* wtd  = wt21 + 1152 * 256;   // dec1: [576][64]

  hipMemsetAsync(ws, 0, 8 * SPL * sizeof(float), stream);  // zero states

  const dim3 blk(256);
  const dim3 blk2(512);

  { // one-time weight transposes (coalesced-dst gather-src)
    TWArgs tw;
    tw.src[0] = c1w[0]; tw.dst[0] = wt10; tw.icn9[0] = 585;  tw.osh[0] = 8;
    tw.src[1] = c1w[1]; tw.dst[1] = wt11; tw.icn9[1] = 1152; tw.osh[1] = 8;
    tw.src[2] = c2w[0]; tw.dst[2] = wt20; tw.icn9[2] = 585;  tw.osh[2] = 8;
    tw.src[3] = c2w[1]; tw.dst[3] = wt21; tw.icn9[3] = 1152; tw.osh[3] = 8;
    tw.src[4] = dw1;    tw.dst[4] = wtd;  tw.icn9[4] = 576;  tw.osh[4] = 6;
    transpose_w<<<dim3(32, 5), blk, 0, stream>>>(tw);
  }

  auto attn_stage = [&](const float* q0, const float* q1, const float* q2, const float* q3,
                        const float* k0, const float* k1, const float* k2, const float* k3,
                        const float* wh, const float* bh, const float* wc, const float* bc,
                        float* o0, float* o1, float* o2, float* o3) {
    QkvArgs qa;
    qa.xq[0]=q0; qa.xq[1]=q1; qa.xq[2]=q2; qa.xq[3]=q3;
    qa.xkv[0]=k0; qa.xkv[1]=k1; qa.xkv[2]=k2; qa.xkv[3]=k3;
    qa.w[0]=wh; qa.w[1]=wc; qa.w[2]=wh; qa.w[3]=wc;
    qa.bias[0]=bh; qa.bias[1]=bc; qa.bias[2]=bh; qa.bias[3]=bc;
    qa.Q=Qb; qa.K=Kb; qa.V=Vb;
    qkv_kernel<<<dim3(16, BB, 12), blk, 0, stream>>>(qa);
    AttnPArgs ap; ap.Q=Qb; ap.K=Kb; ap.V=Vb; ap.pbuf=pbuf;
    attn_part<<<dim3(64, BB, 4), blk, 0, stream>>>(ap);
    AttnMArgs am; am.pbuf=pbuf;
    am.xq[0]=q0; am.xq[1]=q1; am.xq[2]=q2; am.xq[3]=q3;
    am.out[0]=o0; am.out[1]=o1; am.out[2]=o2; am.out[3]=o3;
    attn_merge<<<dim3(16, BB, 4), blk, 0, stream>>>(am);
  };

  auto decode = [&](long off1, long off2, long bstr) {
    Dec1Args d1; d1.in[0] = h1s + SPL; d1.in[1] = h2s + SPL;
    d1.w = wtd; d1.b = db1; d1.tmp = dtmp;
    dec1_kernel<<<dim3(64, BB, 2), blk2, 0, stream>>>(d1);
    Dec2Args d2; d2.tmp = dtmp; d2.w = dw2; d2.b = db2;
    d2.dst0 = out + off1; d2.dst1 = out + off2; d2.bstr = bstr;
    dec2_kernel<<<dim3(64, BB, 2), blk, 0, stream>>>(d2);
  };

  // 6 steps: 3 warm + 3 future-consuming (last future step's state is never read)
  for (int s = 0; s < 6; ++s) {
    const float *x1, *x2; long xbs;
    if (s < 3) { x1 = x1_seq + s * HWN; x2 = x2_seq + s * HWN; xbs = 3 * HWN; }
    else       { x1 = out + (s - 3) * HWN; x2 = out + 8192 + (s - 3) * HWN; xbs = 4 * HWN; }

    for (int l = 0; l < 2; ++l) {
      if (l == 1) { x1 = h1s; x2 = h2s; xbs = (long)HIDC * HWN; }  // layer-0 state (this step)
      CellArgs ca;
      ca.x[0] = x1; ca.x[1] = x2; ca.xbs = xbs;
      ca.h[0] = h1s + l * SPL; ca.h[1] = h2s + l * SPL;
      ca.c[0] = c1s + l * SPL; ca.c[1] = c2s + l * SPL;
      ca.w[0] = (l == 0) ? wt10 : wt11;
      ca.w[1] = (l == 0) ? wt20 : wt21;
      ca.bias[0] = c1b[l]; ca.bias[1] = c2b[l];
      ca.ho[0] = hc1; ca.ho[1] = hc2; ca.co[0] = cc1; ca.co[1] = cc2;
      if (l == 0) cell_kernel<1><<<dim3(64, BB, 2), blk2, 0, stream>>>(ca);
      else        cell_kernel<64><<<dim3(64, BB, 2), blk2, 0, stream>>>(ca);

      // self-attention: (h1,h1,sah) (c1,c1,sac) (h2,h2,sah) (c2,c2,sac)
      attn_stage(hc1, cc1, hc2, cc2,
                 hc1, cc1, hc2, cc2,
                 sah_w + l * 12288, sah_b + l * 192,
                 sac_w + l * 12288, sac_b + l * 192,
                 hs1, cs1, hs2, cs2);
      // cross-attention: (h1,h2,cah) (c1,c2,cac) (h2,tag_h1,cah) (c2,tag_c1,cac)
      attn_stage(hs1, cs1, hs2, cs2,
                 hs2, cs2, hs1, cs1,
                 cah_w + l * 12288, cah_b + l * 192,
                 cac_w + l * 12288, cac_b + l * 192,
                 h1s + l * SPL, c1s + l * SPL, h2s + l * SPL, c2s + l * SPL);
    }

    if (s == 0)      decode(16384,        20480,        2048);  // warm slot 0
    else if (s == 1) decode(16384 + 1024, 20480 + 1024, 2048);  // warm slot 1
    else             decode((s - 2) * HWN, 8192 + (s - 2) * HWN, 4096); // future slots
  }
}